// Round 1
// baseline (6148.186 us; speedup 1.0000x reference)
//
#include <hip/hip_runtime.h>

// SelfAttentionBlock: graph transformer attention
// N=100000 nodes, E=1600000 edges, DIM=64, H=4 heads, d=16
constexpr int N_NODES = 100000;
constexpr int N_EDGES = 1600000;
constexpr int DIM = 64;
constexpr int H = 4;
constexpr int HD = 16;
constexpr float QK_SCALE = 0.25f;   // 16^-0.5
constexpr float EPS = 1e-16f;

// Monotone float<->uint mapping so atomicMax(uint) implements float max.
__device__ __forceinline__ unsigned int enc_f32(float f) {
    unsigned int u = __float_as_uint(f);
    return (u & 0x80000000u) ? ~u : (u | 0x80000000u);
}
__device__ __forceinline__ float dec_f32(unsigned int u) {
    return __uint_as_float((u & 0x80000000u) ? (u & 0x7fffffffu) : ~u);
}

// K0: qkv[n, 0:192] = x[n,:] @ W[:, 0:192] + b.  W staged in LDS.
__global__ __launch_bounds__(192) void qkv_proj(const float* __restrict__ x,
                                                const float* __restrict__ W,
                                                const float* __restrict__ b,
                                                float* __restrict__ qkv) {
    __shared__ float sW[DIM * 192];   // 49152 B
    __shared__ float sB[192];
    for (int i = threadIdx.x; i < DIM * 192; i += 192) sW[i] = W[i];
    sB[threadIdx.x] = b[threadIdx.x];
    __syncthreads();
    const int j = threadIdx.x;
    for (int n = blockIdx.x; n < N_NODES; n += gridDim.x) {
        const float* xr = x + (size_t)n * DIM;
        float acc = sB[j];
        #pragma unroll
        for (int k = 0; k < DIM; ++k)
            acc = fmaf(xr[k], sW[k * 192 + j], acc);   // xr[k] wave-broadcast, sW conflict-free
        qkv[(size_t)n * 192 + j] = acc;
    }
}

// K1: compat[e,h] = scale * dot(q[s,h,:], k[t,h,:]); running max per (s,h).
__global__ __launch_bounds__(256) void compat_pass(const float* __restrict__ qkv,
                                                   const int* __restrict__ ei,
                                                   float* __restrict__ compat,
                                                   unsigned int* __restrict__ m_enc) {
    int tid = blockIdx.x * blockDim.x + threadIdx.x;
    if (tid >= N_EDGES * H) return;
    int e = tid >> 2, h = tid & 3;
    int s = ei[e];
    int t = ei[N_EDGES + e];
    const float4* qp = (const float4*)(qkv + (size_t)s * 192 + h * HD);        // q slot
    const float4* kp = (const float4*)(qkv + (size_t)t * 192 + 64 + h * HD);   // k slot
    float acc = 0.f;
    #pragma unroll
    for (int i = 0; i < 4; ++i) {
        float4 q = qp[i], k = kp[i];
        acc += q.x * k.x + q.y * k.y + q.z * k.z + q.w * k.w;
    }
    acc *= QK_SCALE;
    compat[tid] = acc;                       // layout (E,H): tid == e*4+h
    atomicMax(m_enc + s * H + h, enc_f32(acc));
}

// K2: ex = exp(compat - m[s]); den[s,h] += ex.  ex overwrites compat.
__global__ __launch_bounds__(256) void exp_pass(const int* __restrict__ ei,
                                                const unsigned int* __restrict__ m_enc,
                                                float* __restrict__ compat,
                                                float* __restrict__ den) {
    int tid = blockIdx.x * blockDim.x + threadIdx.x;
    if (tid >= N_EDGES * H) return;
    int e = tid >> 2, h = tid & 3;
    int s = ei[e];
    float m = dec_f32(m_enc[s * H + h]);
    float ex = expf(compat[tid] - m);
    compat[tid] = ex;
    atomicAdd(den + s * H + h, ex);
}

// K3: out[s, h*16+d] += v[t,h,d] * ex/(den[s,h]+eps)
__global__ __launch_bounds__(256) void scatter_pass(const float* __restrict__ qkv,
                                                    const int* __restrict__ ei,
                                                    const float* __restrict__ ex,
                                                    const float* __restrict__ den,
                                                    float* __restrict__ out) {
    int tid = blockIdx.x * blockDim.x + threadIdx.x;
    if (tid >= N_EDGES * H) return;
    int e = tid >> 2, h = tid & 3;
    int s = ei[e];
    int t = ei[N_EDGES + e];
    float a = ex[tid] / (den[s * H + h] + EPS);
    const float4* vp = (const float4*)(qkv + (size_t)t * 192 + 128 + h * HD);  // v slot
    float* op = out + (size_t)s * DIM + h * HD;
    #pragma unroll
    for (int i = 0; i < 4; ++i) {
        float4 v = vp[i];
        atomicAdd(op + 4 * i + 0, v.x * a);
        atomicAdd(op + 4 * i + 1, v.y * a);
        atomicAdd(op + 4 * i + 2, v.z * a);
        atomicAdd(op + 4 * i + 3, v.w * a);
    }
}

extern "C" void kernel_launch(void* const* d_in, const int* in_sizes, int n_in,
                              void* d_out, int out_size, void* d_ws, size_t ws_size,
                              hipStream_t stream) {
    const float* x = (const float*)d_in[0];
    const float* W = (const float*)d_in[1];
    const float* b = (const float*)d_in[2];
    const int*   ei = (const int*)d_in[3];   // (2, E): [0:E]=src, [E:2E]=tgt
    float* out = (float*)d_out;

    // workspace layout (floats): qkv | compat/ex | den | m_enc  = ~105.6 MB
    float* qkv    = (float*)d_ws;
    float* compat = qkv + (size_t)N_NODES * 192;
    float* den    = compat + (size_t)N_EDGES * H;
    unsigned int* m_enc = (unsigned int*)(den + (size_t)N_NODES * H);

    hipMemsetAsync(out, 0, (size_t)N_NODES * DIM * sizeof(float), stream);
    // den and m_enc are adjacent: one memset zeroes both (enc=0 < enc(any float))
    hipMemsetAsync(den, 0, (size_t)N_NODES * H * 2 * sizeof(float), stream);

    qkv_proj<<<1024, 192, 0, stream>>>(x, W, b, qkv);

    const int ethreads = N_EDGES * H;
    const int eblocks = (ethreads + 255) / 256;
    compat_pass<<<eblocks, 256, 0, stream>>>(qkv, ei, compat, m_enc);
    exp_pass<<<eblocks, 256, 0, stream>>>(ei, m_enc, compat, den);
    scatter_pass<<<eblocks, 256, 0, stream>>>(qkv, ei, compat, den, out);
}

// Round 2
// 580.865 us; speedup vs baseline: 10.5845x; 10.5845x over previous
//
#include <hip/hip_runtime.h>

// SelfAttentionBlock: graph transformer attention (CSR + per-node wave pass)
// N=100000 nodes, E=1600000 edges, DIM=64, H=4 heads, d=16
constexpr int N_NODES = 100000;
constexpr int N_EDGES = 1600000;
constexpr int DIM = 64;
constexpr float QK_SCALE = 0.25f;   // 16^-0.5
constexpr float EPS = 1e-16f;

// ---------------- K0: qkv[n, 0:192] = x[n,:] @ W[:, 0:192] + b ----------------
__global__ __launch_bounds__(192) void qkv_proj(const float* __restrict__ x,
                                                const float* __restrict__ W,
                                                const float* __restrict__ b,
                                                float* __restrict__ qkv) {
    __shared__ float sW[DIM * 192];   // 49152 B
    __shared__ float sB[192];
    for (int i = threadIdx.x; i < DIM * 192; i += 192) sW[i] = W[i];
    sB[threadIdx.x] = b[threadIdx.x];
    __syncthreads();
    const int j = threadIdx.x;
    for (int n = blockIdx.x; n < N_NODES; n += gridDim.x) {
        const float* xr = x + (size_t)n * DIM;
        float acc = sB[j];
        #pragma unroll
        for (int k = 0; k < DIM; ++k)
            acc = fmaf(xr[k], sW[k * 192 + j], acc);
        qkv[(size_t)n * 192 + j] = acc;
    }
}

// ---------------- CSR build ----------------
__global__ __launch_bounds__(256) void count_kernel(const int* __restrict__ ei,
                                                    int* __restrict__ deg) {
    int e = blockIdx.x * blockDim.x + threadIdx.x;
    if (e < N_EDGES) atomicAdd(deg + ei[e], 1);
}

// Exclusive scan of deg[0:N] -> off[0:N]; single block, 1024 threads.
__global__ __launch_bounds__(1024) void scan_kernel(const int* __restrict__ deg,
                                                    int* __restrict__ off) {
    __shared__ int s[1024];
    __shared__ int carry;
    const int tid = threadIdx.x;
    if (tid == 0) carry = 0;
    __syncthreads();
    for (int base = 0; base < N_NODES; base += 1024) {
        int v = (base + tid < N_NODES) ? deg[base + tid] : 0;
        s[tid] = v;
        __syncthreads();
        #pragma unroll
        for (int d = 1; d < 1024; d <<= 1) {
            int t = (tid >= d) ? s[tid - d] : 0;
            __syncthreads();
            s[tid] += t;
            __syncthreads();
        }
        int c = carry;                       // all threads read current carry
        if (base + tid < N_NODES) off[base + tid] = s[tid] - v + c;
        __syncthreads();
        if (tid == 0) carry = c + s[1023];   // chunk total
        __syncthreads();
    }
}

// Bin each edge's target node into its source node's CSR segment.
__global__ __launch_bounds__(256) void fill_kernel(const int* __restrict__ ei,
                                                   const int* __restrict__ off,
                                                   int* __restrict__ cursor,
                                                   int* __restrict__ sorted_t) {
    int e = blockIdx.x * blockDim.x + threadIdx.x;
    if (e >= N_EDGES) return;
    int s = ei[e];
    int t = ei[N_EDGES + e];
    int pos = off[s] + atomicAdd(cursor + s, 1);
    sorted_t[pos] = t;
}

// ---------------- Fused per-node attention ----------------
// One wave (64 lanes) per node. lane = h*16 + d. Online softmax, all in regs.
__global__ __launch_bounds__(256) void node_pass(const float* __restrict__ qkv,
                                                 const int* __restrict__ off,
                                                 const int* __restrict__ deg,
                                                 const int* __restrict__ sorted_t,
                                                 float* __restrict__ out) {
    const int node = blockIdx.x * 4 + (threadIdx.x >> 6);
    const int lane = threadIdx.x & 63;
    if (node >= N_NODES) return;

    const int o = off[node];
    const int d = deg[node];

    const float q = qkv[(size_t)node * 192 + lane] * QK_SCALE;
    float m = -__builtin_inff();
    float l = 0.f;
    float acc = 0.f;

    for (int base = 0; base < d; base += 64) {
        const int nb = min(64, d - base);
        // batch-load up to 64 target indices, one per lane (coalesced)
        int tb = (base + lane < d) ? sorted_t[o + base + lane] : 0;
        for (int j = 0; j < nb; ++j) {
            const int t = __shfl(tb, j);
            const float* kp = qkv + (size_t)t * 192;
            const float kv = kp[64 + lane];    // k slot, coalesced 256B
            const float vv = kp[128 + lane];   // v slot, coalesced 256B
            float p = q * kv;
            // reduce within 16-lane head group
            p += __shfl_xor(p, 1);
            p += __shfl_xor(p, 2);
            p += __shfl_xor(p, 4);
            p += __shfl_xor(p, 8);
            const float nm = fmaxf(m, p);
            const float ex = __expf(p - nm);
            const float sc = __expf(m - nm);   // exp(-inf)=0 on first edge
            l = l * sc + ex;
            acc = acc * sc + ex * vv;
            m = nm;
        }
    }
    out[(size_t)node * DIM + lane] = acc / (l + EPS);
}

extern "C" void kernel_launch(void* const* d_in, const int* in_sizes, int n_in,
                              void* d_out, int out_size, void* d_ws, size_t ws_size,
                              hipStream_t stream) {
    const float* x = (const float*)d_in[0];
    const float* W = (const float*)d_in[1];
    const float* b = (const float*)d_in[2];
    const int*   ei = (const int*)d_in[3];   // (2, E): [0:E]=src, [E:2E]=tgt
    float* out = (float*)d_out;

    // workspace layout: qkv(76.8MB) | deg | cursor | off | sorted_t
    float* qkv = (float*)d_ws;
    int* deg      = (int*)(qkv + (size_t)N_NODES * 192);
    int* cursor   = deg + N_NODES;
    int* off      = cursor + N_NODES;
    int* sorted_t = off + N_NODES;

    // zero deg + cursor in one memset (adjacent)
    hipMemsetAsync(deg, 0, (size_t)N_NODES * 2 * sizeof(int), stream);

    qkv_proj<<<1024, 192, 0, stream>>>(x, W, b, qkv);

    const int eblocks = (N_EDGES + 255) / 256;
    count_kernel<<<eblocks, 256, 0, stream>>>(ei, deg);
    scan_kernel<<<1, 1024, 0, stream>>>(deg, off);
    fill_kernel<<<eblocks, 256, 0, stream>>>(ei, off, cursor, sorted_t);

    node_pass<<<(N_NODES + 3) / 4, 256, 0, stream>>>(qkv, off, deg, sorted_t, out);
}

// Round 3
// 365.646 us; speedup vs baseline: 16.8146x; 1.5886x over previous
//
#include <hip/hip_runtime.h>

// SelfAttentionBlock: graph transformer attention (CSR + per-node wave pass)
// N=100000 nodes, E=1600000 edges, DIM=64, H=4 heads, d=16
constexpr int N_NODES = 100000;
constexpr int N_EDGES = 1600000;
constexpr int DIM = 64;
constexpr float QK_SCALE = 0.25f;   // 16^-0.5
constexpr float EPS = 1e-16f;

constexpr int SCAN_CHUNK = 1024;                       // elems per block
constexpr int SCAN_BLOCKS = (N_NODES + SCAN_CHUNK - 1) / SCAN_CHUNK;  // 98

// ---------------- K0: qkv[n, 0:192] = x[n,:] @ W[:, 0:192] + b ----------------
__global__ __launch_bounds__(192) void qkv_proj(const float* __restrict__ x,
                                                const float* __restrict__ W,
                                                const float* __restrict__ b,
                                                float* __restrict__ qkv) {
    __shared__ float sW[DIM * 192];   // 49152 B
    __shared__ float sB[192];
    for (int i = threadIdx.x; i < DIM * 192; i += 192) sW[i] = W[i];
    sB[threadIdx.x] = b[threadIdx.x];
    __syncthreads();
    const int j = threadIdx.x;
    for (int n = blockIdx.x; n < N_NODES; n += gridDim.x) {
        const float* xr = x + (size_t)n * DIM;
        float acc = sB[j];
        #pragma unroll
        for (int k = 0; k < DIM; ++k)
            acc = fmaf(xr[k], sW[k * 192 + j], acc);
        qkv[(size_t)n * 192 + j] = acc;
    }
}

// ---------------- CSR build ----------------
__global__ __launch_bounds__(256) void count_kernel(const int* __restrict__ ei,
                                                    int* __restrict__ deg) {
    int e = blockIdx.x * blockDim.x + threadIdx.x;
    if (e < N_EDGES) atomicAdd(deg + ei[e], 1);
}

// Phase 1: per-block sums of deg (1024 elems/block).
__global__ __launch_bounds__(256) void scan_partial(const int* __restrict__ deg,
                                                    int* __restrict__ bsum) {
    const int tid = threadIdx.x;
    const int base = blockIdx.x * SCAN_CHUNK;
    int sum = 0;
    #pragma unroll
    for (int k = 0; k < 4; ++k) {
        int idx = base + tid * 4 + k;
        sum += (idx < N_NODES) ? deg[idx] : 0;
    }
    #pragma unroll
    for (int d = 1; d < 64; d <<= 1) sum += __shfl_xor(sum, d);
    __shared__ int sW[4];
    if ((tid & 63) == 0) sW[tid >> 6] = sum;
    __syncthreads();
    if (tid == 0) bsum[blockIdx.x] = sW[0] + sW[1] + sW[2] + sW[3];
}

// Phase 2: each block computes its global offset from bsum, then exclusive-scans
// its own 1024-elem chunk and writes off[].
__global__ __launch_bounds__(256) void scan_final(const int* __restrict__ deg,
                                                  const int* __restrict__ bsum,
                                                  int* __restrict__ off) {
    const int tid = threadIdx.x;
    const int lane = tid & 63;
    const int wid = tid >> 6;
    __shared__ int sW[4];
    __shared__ int sOff;

    // block offset = sum of bsum[0 .. blockIdx-1]  (SCAN_BLOCKS=98 <= 256)
    int b = (tid < blockIdx.x) ? bsum[tid] : 0;
    int bs = b;
    #pragma unroll
    for (int d = 1; d < 64; d <<= 1) bs += __shfl_xor(bs, d);
    if (lane == 0) sW[wid] = bs;
    __syncthreads();
    if (tid == 0) sOff = sW[0] + sW[1] + sW[2] + sW[3];
    __syncthreads();

    // local exclusive scan: each thread owns 4 consecutive elements
    const int base = blockIdx.x * SCAN_CHUNK;
    int v[4];
    #pragma unroll
    for (int k = 0; k < 4; ++k) {
        int idx = base + tid * 4 + k;
        v[k] = (idx < N_NODES) ? deg[idx] : 0;
    }
    const int t0 = v[0], t1 = t0 + v[1], t2 = t1 + v[2], T = t2 + v[3];
    int inc = T;
    #pragma unroll
    for (int d = 1; d < 64; d <<= 1) {
        int u = __shfl_up(inc, d);
        if (lane >= d) inc += u;
    }
    const int exc = inc - T;
    if (lane == 63) sW[wid] = inc;   // sW reuse is safe: last read was before 2nd sync
    __syncthreads();
    int woff = 0;
    for (int w = 0; w < wid; ++w) woff += sW[w];
    const int off0 = sOff + woff + exc;

    const int idx0 = base + tid * 4;
    if (idx0     < N_NODES) off[idx0]     = off0;
    if (idx0 + 1 < N_NODES) off[idx0 + 1] = off0 + t0;
    if (idx0 + 2 < N_NODES) off[idx0 + 2] = off0 + t1;
    if (idx0 + 3 < N_NODES) off[idx0 + 3] = off0 + t2;
}

// Bin each edge's target node into its source node's CSR segment.
__global__ __launch_bounds__(256) void fill_kernel(const int* __restrict__ ei,
                                                   const int* __restrict__ off,
                                                   int* __restrict__ cursor,
                                                   int* __restrict__ sorted_t) {
    int e = blockIdx.x * blockDim.x + threadIdx.x;
    if (e >= N_EDGES) return;
    int s = ei[e];
    int t = ei[N_EDGES + e];
    int pos = off[s] + atomicAdd(cursor + s, 1);
    sorted_t[pos] = t;
}

// ---------------- Fused per-node attention ----------------
// One wave (64 lanes) per node. lane = h*16 + d. Online softmax, all in regs.
__global__ __launch_bounds__(256) void node_pass(const float* __restrict__ qkv,
                                                 const int* __restrict__ off,
                                                 const int* __restrict__ deg,
                                                 const int* __restrict__ sorted_t,
                                                 float* __restrict__ out) {
    const int node = blockIdx.x * 4 + (threadIdx.x >> 6);
    const int lane = threadIdx.x & 63;
    if (node >= N_NODES) return;

    const int o = off[node];
    const int d = deg[node];

    const float q = qkv[(size_t)node * 192 + lane] * QK_SCALE;
    float m = -__builtin_inff();
    float l = 0.f;
    float acc = 0.f;

    for (int base = 0; base < d; base += 64) {
        const int nb = min(64, d - base);
        int tb = (base + lane < d) ? sorted_t[o + base + lane] : 0;
        int j = 0;
        for (; j + 2 <= nb; j += 2) {
            const int ta = __shfl(tb, j);
            const int tc = __shfl(tb, j + 1);
            const float* kpa = qkv + (size_t)ta * 192;
            const float* kpc = qkv + (size_t)tc * 192;
            const float ka = kpa[64 + lane],  va = kpa[128 + lane];
            const float kc = kpc[64 + lane],  vc = kpc[128 + lane];
            float pa = q * ka, pc = q * kc;
            pa += __shfl_xor(pa, 1);  pc += __shfl_xor(pc, 1);
            pa += __shfl_xor(pa, 2);  pc += __shfl_xor(pc, 2);
            pa += __shfl_xor(pa, 4);  pc += __shfl_xor(pc, 4);
            pa += __shfl_xor(pa, 8);  pc += __shfl_xor(pc, 8);
            const float nm = fmaxf(m, fmaxf(pa, pc));
            const float ea = __expf(pa - nm);
            const float ec = __expf(pc - nm);
            const float sc = __expf(m - nm);   // exp(-inf)=0 on first pair
            l = l * sc + ea + ec;
            acc = acc * sc + ea * va + ec * vc;
            m = nm;
        }
        if (j < nb) {
            const int t = __shfl(tb, j);
            const float* kp = qkv + (size_t)t * 192;
            const float kv = kp[64 + lane];
            const float vv = kp[128 + lane];
            float p = q * kv;
            p += __shfl_xor(p, 1);
            p += __shfl_xor(p, 2);
            p += __shfl_xor(p, 4);
            p += __shfl_xor(p, 8);
            const float nm = fmaxf(m, p);
            const float ex = __expf(p - nm);
            const float sc = __expf(m - nm);
            l = l * sc + ex;
            acc = acc * sc + ex * vv;
            m = nm;
        }
    }
    out[(size_t)node * DIM + lane] = acc / (l + EPS);
}

extern "C" void kernel_launch(void* const* d_in, const int* in_sizes, int n_in,
                              void* d_out, int out_size, void* d_ws, size_t ws_size,
                              hipStream_t stream) {
    const float* x = (const float*)d_in[0];
    const float* W = (const float*)d_in[1];
    const float* b = (const float*)d_in[2];
    const int*   ei = (const int*)d_in[3];   // (2, E): [0:E]=src, [E:2E]=tgt
    float* out = (float*)d_out;

    // workspace layout: qkv(76.8MB) | deg | cursor | off | bsum | sorted_t
    float* qkv = (float*)d_ws;
    int* deg      = (int*)(qkv + (size_t)N_NODES * 192);
    int* cursor   = deg + N_NODES;
    int* off      = cursor + N_NODES;
    int* bsum     = off + N_NODES;
    int* sorted_t = bsum + 256;

    // zero deg + cursor in one memset (adjacent)
    hipMemsetAsync(deg, 0, (size_t)N_NODES * 2 * sizeof(int), stream);

    qkv_proj<<<1024, 192, 0, stream>>>(x, W, b, qkv);

    const int eblocks = (N_EDGES + 255) / 256;
    count_kernel<<<eblocks, 256, 0, stream>>>(ei, deg);
    scan_partial<<<SCAN_BLOCKS, 256, 0, stream>>>(deg, bsum);
    scan_final<<<SCAN_BLOCKS, 256, 0, stream>>>(deg, bsum, off);
    fill_kernel<<<eblocks, 256, 0, stream>>>(ei, off, cursor, sorted_t);

    node_pass<<<(N_NODES + 3) / 4, 256, 0, stream>>>(qkv, off, deg, sorted_t, out);
}

// Round 4
// 345.518 us; speedup vs baseline: 17.7941x; 1.0583x over previous
//
#include <hip/hip_runtime.h>

// SelfAttentionBlock: graph transformer attention (CSR + per-node wave pass)
// N=100000 nodes, E=1600000 edges, DIM=64, H=4 heads, d=16
constexpr int N_NODES = 100000;
constexpr int N_EDGES = 1600000;
constexpr int DIM = 64;
constexpr float QK_SCALE = 0.25f;   // 16^-0.5
constexpr float EPS = 1e-16f;

constexpr int SCAN_CHUNK = 1024;
constexpr int SCAN_BLOCKS = (N_NODES + SCAN_CHUNK - 1) / SCAN_CHUNK;  // 98

constexpr int QNB = 16;   // nodes per qkv_proj block; 100000 = 16*6250 exact

// ---------------- K0: qkv projection, register-tiled, no LDS ----------------
// Thread j (0..191) owns output column j for QNB nodes. x reads are
// block-uniform (scalarizable); W reads coalesced, L2-resident.
// Writes q_arr (N,64) pre-scaled by QK_SCALE, and kv (N,128) = [k|v].
__global__ __launch_bounds__(192) void qkv_proj(const float* __restrict__ x,
                                                const float* __restrict__ W,
                                                const float* __restrict__ b,
                                                float* __restrict__ q_arr,
                                                float* __restrict__ kv) {
    const int j = threadIdx.x;
    const int n0 = blockIdx.x * QNB;
    const float bj = b[j];
    float acc[QNB];
    #pragma unroll
    for (int i = 0; i < QNB; ++i) acc[i] = bj;
    const float* xb = x + (size_t)n0 * DIM;
    #pragma unroll
    for (int k0 = 0; k0 < DIM; k0 += 4) {
        const float w0 = W[(k0 + 0) * 192 + j];
        const float w1 = W[(k0 + 1) * 192 + j];
        const float w2 = W[(k0 + 2) * 192 + j];
        const float w3 = W[(k0 + 3) * 192 + j];
        #pragma unroll
        for (int i = 0; i < QNB; ++i) {
            const float4 xv = *(const float4*)(xb + i * DIM + k0);
            acc[i] = fmaf(xv.x, w0, acc[i]);
            acc[i] = fmaf(xv.y, w1, acc[i]);
            acc[i] = fmaf(xv.z, w2, acc[i]);
            acc[i] = fmaf(xv.w, w3, acc[i]);
        }
    }
    if (j < 64) {
        #pragma unroll
        for (int i = 0; i < QNB; ++i)
            q_arr[(size_t)(n0 + i) * 64 + j] = acc[i] * QK_SCALE;
    } else {
        const int jj = j - 64;
        #pragma unroll
        for (int i = 0; i < QNB; ++i)
            kv[(size_t)(n0 + i) * 128 + jj] = acc[i];
    }
}

// ---------------- CSR build ----------------
__global__ __launch_bounds__(256) void count_kernel(const int* __restrict__ ei,
                                                    int* __restrict__ deg) {
    int e = blockIdx.x * blockDim.x + threadIdx.x;
    if (e < N_EDGES) atomicAdd(deg + ei[e], 1);
}

__global__ __launch_bounds__(256) void scan_partial(const int* __restrict__ deg,
                                                    int* __restrict__ bsum) {
    const int tid = threadIdx.x;
    const int base = blockIdx.x * SCAN_CHUNK;
    int sum = 0;
    #pragma unroll
    for (int k = 0; k < 4; ++k) {
        int idx = base + tid * 4 + k;
        sum += (idx < N_NODES) ? deg[idx] : 0;
    }
    #pragma unroll
    for (int d = 1; d < 64; d <<= 1) sum += __shfl_xor(sum, d);
    __shared__ int sW[4];
    if ((tid & 63) == 0) sW[tid >> 6] = sum;
    __syncthreads();
    if (tid == 0) bsum[blockIdx.x] = sW[0] + sW[1] + sW[2] + sW[3];
}

__global__ __launch_bounds__(256) void scan_final(const int* __restrict__ deg,
                                                  const int* __restrict__ bsum,
                                                  int* __restrict__ off) {
    const int tid = threadIdx.x;
    const int lane = tid & 63;
    const int wid = tid >> 6;
    __shared__ int sW[4];
    __shared__ int sOff;

    int b = (tid < blockIdx.x) ? bsum[tid] : 0;
    int bs = b;
    #pragma unroll
    for (int d = 1; d < 64; d <<= 1) bs += __shfl_xor(bs, d);
    if (lane == 0) sW[wid] = bs;
    __syncthreads();
    if (tid == 0) sOff = sW[0] + sW[1] + sW[2] + sW[3];
    __syncthreads();

    const int base = blockIdx.x * SCAN_CHUNK;
    int v[4];
    #pragma unroll
    for (int k = 0; k < 4; ++k) {
        int idx = base + tid * 4 + k;
        v[k] = (idx < N_NODES) ? deg[idx] : 0;
    }
    const int t0 = v[0], t1 = t0 + v[1], t2 = t1 + v[2], T = t2 + v[3];
    int inc = T;
    #pragma unroll
    for (int d = 1; d < 64; d <<= 1) {
        int u = __shfl_up(inc, d);
        if (lane >= d) inc += u;
    }
    const int exc = inc - T;
    if (lane == 63) sW[wid] = inc;
    __syncthreads();
    int woff = 0;
    for (int w = 0; w < wid; ++w) woff += sW[w];
    const int off0 = sOff + woff + exc;

    const int idx0 = base + tid * 4;
    if (idx0     < N_NODES) off[idx0]     = off0;
    if (idx0 + 1 < N_NODES) off[idx0 + 1] = off0 + t0;
    if (idx0 + 2 < N_NODES) off[idx0 + 2] = off0 + t1;
    if (idx0 + 3 < N_NODES) off[idx0 + 3] = off0 + t2;
}

__global__ __launch_bounds__(256) void fill_kernel(const int* __restrict__ ei,
                                                   const int* __restrict__ off,
                                                   int* __restrict__ cursor,
                                                   int* __restrict__ sorted_t) {
    int e = blockIdx.x * blockDim.x + threadIdx.x;
    if (e >= N_EDGES) return;
    int s = ei[e];
    int t = ei[N_EDGES + e];
    int pos = off[s] + atomicAdd(cursor + s, 1);
    sorted_t[pos] = t;
}

// ---------------- Fused per-node attention ----------------
// One wave per node; 4 edges processed per step.
// lane = eg*16 + q16: eg = edge slot (0..3), q16 = float4 slot of the 64-dim row.
// Head of a lane: q16>>2 (4 consecutive float4-slots per head).
// Per-lane state: m (per-head max, eg-uniform), l/acc = partial sums over the
// edges seen in this lane's eg slot; rescale factor sc is eg-uniform so the
// partials stay consistent; one cross-eg reduce at the end.
__global__ __launch_bounds__(256) void node_pass(const float* __restrict__ q_arr,
                                                 const float* __restrict__ kv,
                                                 const int* __restrict__ off,
                                                 const int* __restrict__ deg,
                                                 const int* __restrict__ sorted_t,
                                                 float* __restrict__ out) {
    const int node = blockIdx.x * 4 + (threadIdx.x >> 6);
    const int lane = threadIdx.x & 63;
    if (node >= N_NODES) return;
    const int eg = lane >> 4;
    const int q16 = lane & 15;

    const int o = off[node];
    const int d = deg[node];

    const float4 qv = *(const float4*)(q_arr + (size_t)node * 64 + q16 * 4);
    const float NEG_INF = -__builtin_inff();
    float m = NEG_INF;
    float l = 0.f;
    float4 acc = make_float4(0.f, 0.f, 0.f, 0.f);

    for (int base = 0; base < d; base += 64) {
        const int nb = min(64, d - base);
        int tb = (base + lane < d) ? sorted_t[o + base + lane] : 0;
        for (int j4 = 0; j4 < nb; j4 += 4) {
            const int idx = j4 + eg;
            const int t = __shfl(tb, idx);
            const float* kp = kv + (size_t)t * 128;
            const float4 k4 = *(const float4*)(kp + q16 * 4);
            const float4 v4 = *(const float4*)(kp + 64 + q16 * 4);
            float p = qv.x * k4.x + qv.y * k4.y + qv.z * k4.z + qv.w * k4.w;
            p += __shfl_xor(p, 1);
            p += __shfl_xor(p, 2);             // per-head dot, valid in this quad
            p = (idx < nb) ? p : NEG_INF;      // mask invalid edge slots
            float pm = fmaxf(p, __shfl_xor(p, 16));
            pm = fmaxf(pm, __shfl_xor(pm, 32));   // max over the 4 edges
            const float nm = fmaxf(m, pm);
            const float sc = __expf(m - nm);   // eg-uniform
            const float ex = __expf(p - nm);   // 0 for invalid slots
            l = l * sc + ex;
            acc.x = acc.x * sc + ex * v4.x;
            acc.y = acc.y * sc + ex * v4.y;
            acc.z = acc.z * sc + ex * v4.z;
            acc.w = acc.w * sc + ex * v4.w;
            m = nm;
        }
    }
    // cross-eg reductions (butterfly → all lanes hold the total)
    l += __shfl_xor(l, 16);  l += __shfl_xor(l, 32);
    acc.x += __shfl_xor(acc.x, 16);  acc.x += __shfl_xor(acc.x, 32);
    acc.y += __shfl_xor(acc.y, 16);  acc.y += __shfl_xor(acc.y, 32);
    acc.z += __shfl_xor(acc.z, 16);  acc.z += __shfl_xor(acc.z, 32);
    acc.w += __shfl_xor(acc.w, 16);  acc.w += __shfl_xor(acc.w, 32);

    if (eg == 0) {
        const float inv = 1.f / (l + EPS);
        float4 r = make_float4(acc.x * inv, acc.y * inv, acc.z * inv, acc.w * inv);
        *(float4*)(out + (size_t)node * DIM + q16 * 4) = r;
    }
}

extern "C" void kernel_launch(void* const* d_in, const int* in_sizes, int n_in,
                              void* d_out, int out_size, void* d_ws, size_t ws_size,
                              hipStream_t stream) {
    const float* x = (const float*)d_in[0];
    const float* W = (const float*)d_in[1];
    const float* b = (const float*)d_in[2];
    const int*   ei = (const int*)d_in[3];   // (2, E): [0:E]=src, [E:2E]=tgt
    float* out = (float*)d_out;

    // workspace: q_arr(25.6MB) | kv(51.2MB) | deg | cursor | off | bsum | sorted_t
    float* q_arr = (float*)d_ws;
    float* kv    = q_arr + (size_t)N_NODES * 64;
    int* deg      = (int*)(kv + (size_t)N_NODES * 128);
    int* cursor   = deg + N_NODES;
    int* off      = cursor + N_NODES;
    int* bsum     = off + N_NODES;
    int* sorted_t = bsum + 256;

    hipMemsetAsync(deg, 0, (size_t)N_NODES * 2 * sizeof(int), stream);

    qkv_proj<<<N_NODES / QNB, 192, 0, stream>>>(x, W, b, q_arr, kv);

    const int eblocks = (N_EDGES + 255) / 256;
    count_kernel<<<eblocks, 256, 0, stream>>>(ei, deg);
    scan_partial<<<SCAN_BLOCKS, 256, 0, stream>>>(deg, bsum);
    scan_final<<<SCAN_BLOCKS, 256, 0, stream>>>(deg, bsum, off);
    fill_kernel<<<eblocks, 256, 0, stream>>>(ei, off, cursor, sorted_t);

    node_pass<<<(N_NODES + 3) / 4, 256, 0, stream>>>(q_arr, kv, off, deg, sorted_t, out);
}

// Round 5
// 267.814 us; speedup vs baseline: 22.9569x; 1.2901x over previous
//
#include <hip/hip_runtime.h>

// SelfAttentionBlock: graph transformer attention (CSR + per-node wave pass)
// N=100000 nodes, E=1600000 edges, DIM=64, H=4 heads, d=16
constexpr int N_NODES = 100000;
constexpr int N_EDGES = 1600000;
constexpr int DIM = 64;
constexpr float QK_SCALE = 0.25f;   // 16^-0.5
constexpr float EPS = 1e-16f;

constexpr int SCAN_CHUNK = 1024;
constexpr int SCAN_BLOCKS = (N_NODES + SCAN_CHUNK - 1) / SCAN_CHUNK;  // 98
constexpr int QNB = 16;                       // nodes per qkv block
constexpr int QBLOCKS = N_NODES / QNB;        // 6250 (exact)

__device__ __forceinline__ unsigned short f32_to_bf16_rne(float f) {
    unsigned int u = __float_as_uint(f);
    u += 0x7fffu + ((u >> 16) & 1u);          // round-to-nearest-even
    return (unsigned short)(u >> 16);
}

// ---------------- K0: qkv projection (register-tiled) + fused edge count ----
// Thread j (0..191) owns output column j for QNB nodes. x reads are
// block-uniform (s_load); W reads coalesced, L2-resident.
// q_arr (N,64) f32 pre-scaled; kv (N,128) bf16 = [k|v] (one 256B row = 2 lines).
__global__ __launch_bounds__(192) void qkv_count(const float* __restrict__ x,
                                                 const float* __restrict__ W,
                                                 const float* __restrict__ b,
                                                 const int* __restrict__ ei,
                                                 float* __restrict__ q_arr,
                                                 unsigned short* __restrict__ kv,
                                                 int* __restrict__ deg) {
    // fused CSR count (grid-stride; atomics hide under the FMA chains below)
    {
        const int stride = QBLOCKS * 192;
        for (int e = blockIdx.x * 192 + threadIdx.x; e < N_EDGES; e += stride)
            atomicAdd(deg + ei[e], 1);
    }

    const int j = threadIdx.x;
    const int n0 = blockIdx.x * QNB;
    const float bj = b[j];
    float acc[QNB];
    #pragma unroll
    for (int i = 0; i < QNB; ++i) acc[i] = bj;
    const float* xb = x + (size_t)n0 * DIM;
    #pragma unroll
    for (int k0 = 0; k0 < DIM; k0 += 4) {
        const float w0 = W[(k0 + 0) * 192 + j];
        const float w1 = W[(k0 + 1) * 192 + j];
        const float w2 = W[(k0 + 2) * 192 + j];
        const float w3 = W[(k0 + 3) * 192 + j];
        #pragma unroll
        for (int i = 0; i < QNB; ++i) {
            const float4 xv = *(const float4*)(xb + i * DIM + k0);
            acc[i] = fmaf(xv.x, w0, acc[i]);
            acc[i] = fmaf(xv.y, w1, acc[i]);
            acc[i] = fmaf(xv.z, w2, acc[i]);
            acc[i] = fmaf(xv.w, w3, acc[i]);
        }
    }
    if (j < 64) {
        #pragma unroll
        for (int i = 0; i < QNB; ++i)
            q_arr[(size_t)(n0 + i) * 64 + j] = acc[i] * QK_SCALE;
    } else {
        const int jj = j - 64;
        #pragma unroll
        for (int i = 0; i < QNB; ++i)
            kv[(size_t)(n0 + i) * 128 + jj] = f32_to_bf16_rne(acc[i]);
    }
}

// ---------------- Single-kernel exclusive scan ----------------
// Block B sums deg[0 : B*1024) directly (L2-resident, <=20MB total across
// blocks), then exclusive-scans its own 1024-elem chunk.
__global__ __launch_bounds__(256) void scan_one(const int* __restrict__ deg,
                                                int* __restrict__ off) {
    const int tid = threadIdx.x;
    const int lane = tid & 63;
    const int wid = tid >> 6;
    __shared__ int sW[4];
    __shared__ int sOff;

    // phase 1: block offset = sum of all preceding deg entries
    int prev = 0;
    const int nprev4 = (blockIdx.x * SCAN_CHUNK) >> 2;   // chunk is 16B-aligned
    const int4* d4 = (const int4*)deg;
    for (int i = tid; i < nprev4; i += 256) {
        const int4 v = d4[i];
        prev += v.x + v.y + v.z + v.w;
    }
    #pragma unroll
    for (int d = 1; d < 64; d <<= 1) prev += __shfl_xor(prev, d);
    if (lane == 0) sW[wid] = prev;
    __syncthreads();
    if (tid == 0) sOff = sW[0] + sW[1] + sW[2] + sW[3];
    __syncthreads();

    // phase 2: local exclusive scan (4 consecutive elems per thread)
    const int base = blockIdx.x * SCAN_CHUNK;
    int v[4];
    #pragma unroll
    for (int k = 0; k < 4; ++k) {
        int idx = base + tid * 4 + k;
        v[k] = (idx < N_NODES) ? deg[idx] : 0;
    }
    const int t0 = v[0], t1 = t0 + v[1], t2 = t1 + v[2], T = t2 + v[3];
    int inc = T;
    #pragma unroll
    for (int d = 1; d < 64; d <<= 1) {
        int u = __shfl_up(inc, d);
        if (lane >= d) inc += u;
    }
    const int exc = inc - T;
    if (lane == 63) sW[wid] = inc;
    __syncthreads();
    int woff = 0;
    for (int w = 0; w < wid; ++w) woff += sW[w];
    const int off0 = sOff + woff + exc;

    const int idx0 = base + tid * 4;
    if (idx0     < N_NODES) off[idx0]     = off0;
    if (idx0 + 1 < N_NODES) off[idx0 + 1] = off0 + t0;
    if (idx0 + 2 < N_NODES) off[idx0 + 2] = off0 + t1;
    if (idx0 + 3 < N_NODES) off[idx0 + 3] = off0 + t2;
}

// Bin each edge's target into its source's CSR segment (4 edges/thread).
__global__ __launch_bounds__(256) void fill_kernel(const int* __restrict__ ei,
                                                   const int* __restrict__ off,
                                                   int* __restrict__ cursor,
                                                   int* __restrict__ sorted_t) {
    const int e4 = blockIdx.x * 256 + threadIdx.x;
    if (e4 >= N_EDGES / 4) return;
    const int4 s4 = ((const int4*)ei)[e4];
    const int4 t4 = ((const int4*)(ei + N_EDGES))[e4];
    int pos;
    pos = off[s4.x] + atomicAdd(cursor + s4.x, 1); sorted_t[pos] = t4.x;
    pos = off[s4.y] + atomicAdd(cursor + s4.y, 1); sorted_t[pos] = t4.y;
    pos = off[s4.z] + atomicAdd(cursor + s4.z, 1); sorted_t[pos] = t4.z;
    pos = off[s4.w] + atomicAdd(cursor + s4.w, 1); sorted_t[pos] = t4.w;
}

// ---------------- Fused per-node attention ----------------
// One wave per node; 4 edges per step. lane = eg*16 + q16.
// k/v gathered as bf16 (256 B per edge = 2 cache lines).
__global__ __launch_bounds__(256) void node_pass(const float* __restrict__ q_arr,
                                                 const unsigned short* __restrict__ kv,
                                                 const int* __restrict__ off,
                                                 const int* __restrict__ deg,
                                                 const int* __restrict__ sorted_t,
                                                 float* __restrict__ out) {
    const int node = blockIdx.x * 4 + (threadIdx.x >> 6);
    const int lane = threadIdx.x & 63;
    if (node >= N_NODES) return;
    const int eg = lane >> 4;
    const int q16 = lane & 15;

    const int o = off[node];
    const int d = deg[node];

    const float4 qv = *(const float4*)(q_arr + (size_t)node * 64 + q16 * 4);
    const float NEG_INF = -__builtin_inff();
    float m = NEG_INF;
    float l = 0.f;
    float4 acc = make_float4(0.f, 0.f, 0.f, 0.f);

    for (int base = 0; base < d; base += 64) {
        const int nb = min(64, d - base);
        int tb = (base + lane < d) ? sorted_t[o + base + lane] : 0;
        for (int j4 = 0; j4 < nb; j4 += 4) {
            const int idx = j4 + eg;
            const int t = __shfl(tb, idx);
            const unsigned short* kp = kv + (size_t)t * 128;
            const uint2 ku = *(const uint2*)(kp + q16 * 4);
            const uint2 vu = *(const uint2*)(kp + 64 + q16 * 4);
            const float k0 = __uint_as_float(ku.x << 16);
            const float k1 = __uint_as_float(ku.x & 0xffff0000u);
            const float k2 = __uint_as_float(ku.y << 16);
            const float k3 = __uint_as_float(ku.y & 0xffff0000u);
            float p = qv.x * k0 + qv.y * k1 + qv.z * k2 + qv.w * k3;
            p += __shfl_xor(p, 1);
            p += __shfl_xor(p, 2);             // per-head dot within quad
            p = (idx < nb) ? p : NEG_INF;      // mask invalid edge slots
            float pm = fmaxf(p, __shfl_xor(p, 16));
            pm = fmaxf(pm, __shfl_xor(pm, 32));   // max over the 4 edges
            const float nm = fmaxf(m, pm);
            const float sc = __expf(m - nm);   // eg-uniform
            const float ex = __expf(p - nm);   // 0 for invalid slots
            const float v0 = __uint_as_float(vu.x << 16);
            const float v1 = __uint_as_float(vu.x & 0xffff0000u);
            const float v2 = __uint_as_float(vu.y << 16);
            const float v3 = __uint_as_float(vu.y & 0xffff0000u);
            l = l * sc + ex;
            acc.x = acc.x * sc + ex * v0;
            acc.y = acc.y * sc + ex * v1;
            acc.z = acc.z * sc + ex * v2;
            acc.w = acc.w * sc + ex * v3;
            m = nm;
        }
    }
    // cross-eg reductions (butterfly)
    l += __shfl_xor(l, 16);  l += __shfl_xor(l, 32);
    acc.x += __shfl_xor(acc.x, 16);  acc.x += __shfl_xor(acc.x, 32);
    acc.y += __shfl_xor(acc.y, 16);  acc.y += __shfl_xor(acc.y, 32);
    acc.z += __shfl_xor(acc.z, 16);  acc.z += __shfl_xor(acc.z, 32);
    acc.w += __shfl_xor(acc.w, 16);  acc.w += __shfl_xor(acc.w, 32);

    if (eg == 0) {
        const float inv = 1.f / (l + EPS);
        float4 r = make_float4(acc.x * inv, acc.y * inv, acc.z * inv, acc.w * inv);
        *(float4*)(out + (size_t)node * DIM + q16 * 4) = r;
    }
}

extern "C" void kernel_launch(void* const* d_in, const int* in_sizes, int n_in,
                              void* d_out, int out_size, void* d_ws, size_t ws_size,
                              hipStream_t stream) {
    const float* x = (const float*)d_in[0];
    const float* W = (const float*)d_in[1];
    const float* b = (const float*)d_in[2];
    const int*   ei = (const int*)d_in[3];   // (2, E): [0:E]=src, [E:2E]=tgt
    float* out = (float*)d_out;

    // workspace: q_arr f32(25.6MB) | kv bf16(25.6MB) | deg | cursor | off | sorted_t
    float* q_arr = (float*)d_ws;
    unsigned short* kv = (unsigned short*)(q_arr + (size_t)N_NODES * 64);
    int* deg      = (int*)(kv + (size_t)N_NODES * 128);
    int* cursor   = deg + N_NODES;
    int* off      = cursor + N_NODES;
    int* sorted_t = off + N_NODES;

    // zero deg + cursor in one memset (adjacent)
    hipMemsetAsync(deg, 0, (size_t)N_NODES * 2 * sizeof(int), stream);

    qkv_count<<<QBLOCKS, 192, 0, stream>>>(x, W, b, ei, q_arr, kv, deg);
    scan_one<<<SCAN_BLOCKS, 256, 0, stream>>>(deg, off);
    fill_kernel<<<(N_EDGES / 4 + 255) / 256, 256, 0, stream>>>(ei, off, cursor, sorted_t);
    node_pass<<<(N_NODES + 3) / 4, 256, 0, stream>>>(q_arr, kv, off, deg, sorted_t, out);
}

// Round 6
// 243.249 us; speedup vs baseline: 25.2753x; 1.1010x over previous
//
#include <hip/hip_runtime.h>

// SelfAttentionBlock: graph transformer attention
// N=100000 nodes, E=1600000 edges, DIM=64, H=4 heads, d=16
constexpr int N_NODES = 100000;
constexpr int N_EDGES = 1600000;
constexpr int DIM = 64;
constexpr float QK_SCALE = 0.25f;   // 16^-0.5
constexpr float EPS = 1e-16f;

constexpr int SCAN_CHUNK = 1024;
constexpr int SCAN_BLOCKS = (N_NODES + SCAN_CHUNK - 1) / SCAN_CHUNK;  // 98
constexpr int QNB = 16;                       // nodes per qkv block
constexpr int QBLOCKS = N_NODES / QNB;        // 6250 (exact)

// bucket sort: bucket = s>>8 (256 nodes each), 4 sub-buckets to cut atomic contention
constexpr int NBK = (N_NODES + 255) / 256;    // 391
constexpr int NSUB = 4;
constexpr int SUBCAP = 2048;                  // mean ~1023, sigma ~32 -> 32 sigma headroom
constexpr int BCAP = NSUB * SUBCAP;           // 8192 int2 per bucket
constexpr int CPAD = 32;                      // ints per counter (own cacheline)

__device__ __forceinline__ unsigned short f32_to_bf16_rne(float f) {
    unsigned int u = __float_as_uint(f);
    u += 0x7fffu + ((u >> 16) & 1u);          // round-to-nearest-even
    return (unsigned short)(u >> 16);
}

// ---------------- K0: qkv projection (register-tiled, no LDS, no atomics) ---
// Thread j (0..191) owns output column j for QNB nodes. x reads block-uniform,
// W reads coalesced L2-resident. q_arr (N,64) f32 pre-scaled; kv (N,128) bf16.
__global__ __launch_bounds__(192) void qkv_proj(const float* __restrict__ x,
                                                const float* __restrict__ W,
                                                const float* __restrict__ b,
                                                float* __restrict__ q_arr,
                                                unsigned short* __restrict__ kv) {
    const int j = threadIdx.x;
    const int n0 = blockIdx.x * QNB;
    const float bj = b[j];
    float acc[QNB];
    #pragma unroll
    for (int i = 0; i < QNB; ++i) acc[i] = bj;
    const float* xb = x + (size_t)n0 * DIM;
    #pragma unroll
    for (int k0 = 0; k0 < DIM; k0 += 4) {
        const float w0 = W[(k0 + 0) * 192 + j];
        const float w1 = W[(k0 + 1) * 192 + j];
        const float w2 = W[(k0 + 2) * 192 + j];
        const float w3 = W[(k0 + 3) * 192 + j];
        #pragma unroll
        for (int i = 0; i < QNB; ++i) {
            const float4 xv = *(const float4*)(xb + i * DIM + k0);
            acc[i] = fmaf(xv.x, w0, acc[i]);
            acc[i] = fmaf(xv.y, w1, acc[i]);
            acc[i] = fmaf(xv.z, w2, acc[i]);
            acc[i] = fmaf(xv.w, w3, acc[i]);
        }
    }
    if (j < 64) {
        #pragma unroll
        for (int i = 0; i < QNB; ++i)
            q_arr[(size_t)(n0 + i) * 64 + j] = acc[i] * QK_SCALE;
    } else {
        const int jj = j - 64;
        #pragma unroll
        for (int i = 0; i < QNB; ++i)
            kv[(size_t)(n0 + i) * 128 + jj] = f32_to_bf16_rne(acc[i]);
    }
}

// ---------------- Bucket scatter: edge -> (s>>8) bucket, dense int2 streams --
// Sub-bucket by blockIdx&3: quarters per-counter contention; writes stay
// sequential per (bucket,sub) -> ~1x write amplification.
__global__ __launch_bounds__(256) void bucket_scatter(const int* __restrict__ ei,
                                                      int* __restrict__ bcnt,
                                                      int2* __restrict__ bbuf) {
    const int e4 = blockIdx.x * 256 + threadIdx.x;
    if (e4 >= N_EDGES / 4) return;
    const int sub = blockIdx.x & (NSUB - 1);
    const int4 s4 = ((const int4*)ei)[e4];
    const int4 t4 = ((const int4*)(ei + N_EDGES))[e4];
    #pragma unroll
    for (int k = 0; k < 4; ++k) {
        const int s = (k == 0) ? s4.x : (k == 1) ? s4.y : (k == 2) ? s4.z : s4.w;
        const int t = (k == 0) ? t4.x : (k == 1) ? t4.y : (k == 2) ? t4.z : t4.w;
        const int bk = s >> 8;
        const int pos = atomicAdd(bcnt + (bk * NSUB + sub) * CPAD, 1);
        bbuf[(size_t)bk * BCAP + sub * SUBCAP + pos] = make_int2(s, t);
    }
}

// ---------------- deg via LDS histogram (one block per bucket) --------------
__global__ __launch_bounds__(256) void deg_hist(const int* __restrict__ bcnt,
                                                const int2* __restrict__ bbuf,
                                                int* __restrict__ deg) {
    __shared__ int h[256];
    const int tid = threadIdx.x;
    const int bk = blockIdx.x;
    h[tid] = 0;
    __syncthreads();
    #pragma unroll
    for (int sub = 0; sub < NSUB; ++sub) {
        const int n = bcnt[(bk * NSUB + sub) * CPAD];
        const int2* p = bbuf + (size_t)bk * BCAP + sub * SUBCAP;
        for (int i = tid; i < n; i += 256)
            atomicAdd(&h[p[i].x & 255], 1);
    }
    __syncthreads();
    const int node = bk * 256 + tid;
    if (node < N_NODES) deg[node] = h[tid];
}

// ---------------- Single-kernel exclusive scan ----------------
__global__ __launch_bounds__(256) void scan_one(const int* __restrict__ deg,
                                                int* __restrict__ off) {
    const int tid = threadIdx.x;
    const int lane = tid & 63;
    const int wid = tid >> 6;
    __shared__ int sW[4];
    __shared__ int sOff;

    int prev = 0;
    const int nprev4 = (blockIdx.x * SCAN_CHUNK) >> 2;
    const int4* d4 = (const int4*)deg;
    for (int i = tid; i < nprev4; i += 256) {
        const int4 v = d4[i];
        prev += v.x + v.y + v.z + v.w;
    }
    #pragma unroll
    for (int d = 1; d < 64; d <<= 1) prev += __shfl_xor(prev, d);
    if (lane == 0) sW[wid] = prev;
    __syncthreads();
    if (tid == 0) sOff = sW[0] + sW[1] + sW[2] + sW[3];
    __syncthreads();

    const int base = blockIdx.x * SCAN_CHUNK;
    int v[4];
    #pragma unroll
    for (int k = 0; k < 4; ++k) {
        int idx = base + tid * 4 + k;
        v[k] = (idx < N_NODES) ? deg[idx] : 0;
    }
    const int t0 = v[0], t1 = t0 + v[1], t2 = t1 + v[2], T = t2 + v[3];
    int inc = T;
    #pragma unroll
    for (int d = 1; d < 64; d <<= 1) {
        int u = __shfl_up(inc, d);
        if (lane >= d) inc += u;
    }
    const int exc = inc - T;
    if (lane == 63) sW[wid] = inc;
    __syncthreads();
    int woff = 0;
    for (int w = 0; w < wid; ++w) woff += sW[w];
    const int off0 = sOff + woff + exc;

    const int idx0 = base + tid * 4;
    if (idx0     < N_NODES) off[idx0]     = off0;
    if (idx0 + 1 < N_NODES) off[idx0 + 1] = off0 + t0;
    if (idx0 + 2 < N_NODES) off[idx0 + 2] = off0 + t1;
    if (idx0 + 3 < N_NODES) off[idx0 + 3] = off0 + t2;
}

// ---------------- CSR fill via LDS cursors (one block per bucket) -----------
// Destination window per bucket ~16KB -> L2-hot, ~1x write amplification.
__global__ __launch_bounds__(256) void csr_fill(const int* __restrict__ bcnt,
                                                const int2* __restrict__ bbuf,
                                                const int* __restrict__ off,
                                                int* __restrict__ sorted_t) {
    __shared__ int cur[256];
    const int tid = threadIdx.x;
    const int bk = blockIdx.x;
    cur[tid] = 0;
    __syncthreads();
    #pragma unroll
    for (int sub = 0; sub < NSUB; ++sub) {
        const int n = bcnt[(bk * NSUB + sub) * CPAD];
        const int2* p = bbuf + (size_t)bk * BCAP + sub * SUBCAP;
        for (int i = tid; i < n; i += 256) {
            const int2 e = p[i];
            const int c = atomicAdd(&cur[e.x & 255], 1);
            sorted_t[off[e.x] + c] = e.y;
        }
    }
}

// ---------------- Fused per-node attention ----------------
// One wave per node; 4 edges per step. lane = eg*16 + q16. bf16 k/v.
__global__ __launch_bounds__(256) void node_pass(const float* __restrict__ q_arr,
                                                 const unsigned short* __restrict__ kv,
                                                 const int* __restrict__ off,
                                                 const int* __restrict__ deg,
                                                 const int* __restrict__ sorted_t,
                                                 float* __restrict__ out) {
    const int node = blockIdx.x * 4 + (threadIdx.x >> 6);
    const int lane = threadIdx.x & 63;
    if (node >= N_NODES) return;
    const int eg = lane >> 4;
    const int q16 = lane & 15;

    const int o = off[node];
    const int d = deg[node];

    const float4 qv = *(const float4*)(q_arr + (size_t)node * 64 + q16 * 4);
    const float NEG_INF = -__builtin_inff();
    float m = NEG_INF;
    float l = 0.f;
    float4 acc = make_float4(0.f, 0.f, 0.f, 0.f);

    for (int base = 0; base < d; base += 64) {
        const int nb = min(64, d - base);
        int tb = (base + lane < d) ? sorted_t[o + base + lane] : 0;
        for (int j4 = 0; j4 < nb; j4 += 4) {
            const int idx = j4 + eg;
            const int t = __shfl(tb, idx);
            const unsigned short* kp = kv + (size_t)t * 128;
            const uint2 ku = *(const uint2*)(kp + q16 * 4);
            const uint2 vu = *(const uint2*)(kp + 64 + q16 * 4);
            const float k0 = __uint_as_float(ku.x << 16);
            const float k1 = __uint_as_float(ku.x & 0xffff0000u);
            const float k2 = __uint_as_float(ku.y << 16);
            const float k3 = __uint_as_float(ku.y & 0xffff0000u);
            float p = qv.x * k0 + qv.y * k1 + qv.z * k2 + qv.w * k3;
            p += __shfl_xor(p, 1);
            p += __shfl_xor(p, 2);             // per-head dot within quad
            p = (idx < nb) ? p : NEG_INF;      // mask invalid edge slots
            float pm = fmaxf(p, __shfl_xor(p, 16));
            pm = fmaxf(pm, __shfl_xor(pm, 32));   // max over the 4 edges
            const float nm = fmaxf(m, pm);
            const float sc = __expf(m - nm);   // eg-uniform
            const float ex = __expf(p - nm);   // 0 for invalid slots
            const float v0 = __uint_as_float(vu.x << 16);
            const float v1 = __uint_as_float(vu.x & 0xffff0000u);
            const float v2 = __uint_as_float(vu.y << 16);
            const float v3 = __uint_as_float(vu.y & 0xffff0000u);
            l = l * sc + ex;
            acc.x = acc.x * sc + ex * v0;
            acc.y = acc.y * sc + ex * v1;
            acc.z = acc.z * sc + ex * v2;
            acc.w = acc.w * sc + ex * v3;
            m = nm;
        }
    }
    l += __shfl_xor(l, 16);  l += __shfl_xor(l, 32);
    acc.x += __shfl_xor(acc.x, 16);  acc.x += __shfl_xor(acc.x, 32);
    acc.y += __shfl_xor(acc.y, 16);  acc.y += __shfl_xor(acc.y, 32);
    acc.z += __shfl_xor(acc.z, 16);  acc.z += __shfl_xor(acc.z, 32);
    acc.w += __shfl_xor(acc.w, 16);  acc.w += __shfl_xor(acc.w, 32);

    if (eg == 0) {
        const float inv = 1.f / (l + EPS);
        float4 r = make_float4(acc.x * inv, acc.y * inv, acc.z * inv, acc.w * inv);
        *(float4*)(out + (size_t)node * DIM + q16 * 4) = r;
    }
}

extern "C" void kernel_launch(void* const* d_in, const int* in_sizes, int n_in,
                              void* d_out, int out_size, void* d_ws, size_t ws_size,
                              hipStream_t stream) {
    const float* x = (const float*)d_in[0];
    const float* W = (const float*)d_in[1];
    const float* b = (const float*)d_in[2];
    const int*   ei = (const int*)d_in[3];   // (2, E): [0:E]=src, [E:2E]=tgt
    float* out = (float*)d_out;

    // workspace: q_arr 25.6MB | kv 25.6MB | bbuf 25.6MB | sorted_t 6.4MB | deg | off | bcnt
    float* q_arr = (float*)d_ws;
    unsigned short* kv = (unsigned short*)(q_arr + (size_t)N_NODES * 64);
    int2* bbuf    = (int2*)(kv + (size_t)N_NODES * 128);
    int* sorted_t = (int*)(bbuf + (size_t)NBK * BCAP);
    int* deg      = sorted_t + N_EDGES;
    int* off      = deg + N_NODES;
    int* bcnt     = off + N_NODES;

    hipMemsetAsync(bcnt, 0, (size_t)NBK * NSUB * CPAD * sizeof(int), stream);

    qkv_proj<<<QBLOCKS, 192, 0, stream>>>(x, W, b, q_arr, kv);
    bucket_scatter<<<(N_EDGES / 4 + 255) / 256, 256, 0, stream>>>(ei, bcnt, bbuf);
    deg_hist<<<NBK, 256, 0, stream>>>(bcnt, bbuf, deg);
    scan_one<<<SCAN_BLOCKS, 256, 0, stream>>>(deg, off);
    csr_fill<<<NBK, 256, 0, stream>>>(bcnt, bbuf, off, sorted_t);
    node_pass<<<(N_NODES + 3) / 4, 256, 0, stream>>>(q_arr, kv, off, deg, sorted_t, out);
}

// Round 7
// 155.811 us; speedup vs baseline: 39.4592x; 1.5612x over previous
//
#include <hip/hip_runtime.h>

// SelfAttentionBlock: graph transformer attention
// N=100000 nodes, E=1600000 edges, DIM=64, H=4 heads, d=16
constexpr int N_NODES = 100000;
constexpr int N_EDGES = 1600000;
constexpr int DIM = 64;
constexpr float QK_SCALE = 0.25f;   // 16^-0.5
constexpr float EPS = 1e-16f;

constexpr int QNB = 16;                       // nodes per qkv block
constexpr int QBLOCKS = N_NODES / QNB;        // 6250 (exact)

// bucket sort: bucket = s>>8 (256 nodes each)
constexpr int NBK = (N_NODES + 255) / 256;    // 391
constexpr int BCAP = 8192;                    // u32/bucket: mean 4092, sigma 64 -> 64 sigma
constexpr int SC_CHUNK = 8192;                // edges per scatter block
constexpr int SC_THREADS = 512;
constexpr int SC_BLOCKS = (N_EDGES + SC_CHUNK - 1) / SC_CHUNK;  // 196

__device__ __forceinline__ unsigned short f32_to_bf16_rne(float f) {
    unsigned int u = __float_as_uint(f);
    u += 0x7fffu + ((u >> 16) & 1u);          // round-to-nearest-even
    return (unsigned short)(u >> 16);
}

// ---------------- K0: qkv projection (register-tiled) + bcnt zeroing --------
__global__ __launch_bounds__(192) void qkv_proj(const float* __restrict__ x,
                                                const float* __restrict__ W,
                                                const float* __restrict__ b,
                                                float* __restrict__ q_arr,
                                                unsigned short* __restrict__ kv,
                                                int* __restrict__ bcnt) {
    const int j = threadIdx.x;
    if (blockIdx.x == 0)                       // zero bcnt for the scatter kernel
        for (int i = j; i < NBK; i += 192) bcnt[i] = 0;

    const int n0 = blockIdx.x * QNB;
    const float bj = b[j];
    float acc[QNB];
    #pragma unroll
    for (int i = 0; i < QNB; ++i) acc[i] = bj;
    const float* xb = x + (size_t)n0 * DIM;
    #pragma unroll
    for (int k0 = 0; k0 < DIM; k0 += 4) {
        const float w0 = W[(k0 + 0) * 192 + j];
        const float w1 = W[(k0 + 1) * 192 + j];
        const float w2 = W[(k0 + 2) * 192 + j];
        const float w3 = W[(k0 + 3) * 192 + j];
        #pragma unroll
        for (int i = 0; i < QNB; ++i) {
            const float4 xv = *(const float4*)(xb + i * DIM + k0);
            acc[i] = fmaf(xv.x, w0, acc[i]);
            acc[i] = fmaf(xv.y, w1, acc[i]);
            acc[i] = fmaf(xv.z, w2, acc[i]);
            acc[i] = fmaf(xv.w, w3, acc[i]);
        }
    }
    if (j < 64) {
        #pragma unroll
        for (int i = 0; i < QNB; ++i)
            q_arr[(size_t)(n0 + i) * 64 + j] = acc[i] * QK_SCALE;
    } else {
        const int jj = j - 64;
        #pragma unroll
        for (int i = 0; i < QNB; ++i)
            kv[(size_t)(n0 + i) * 128 + jj] = f32_to_bf16_rne(acc[i]);
    }
}

// ---------------- Bucket scatter with LDS dense staging ----------------
// Per block: histogram chunk -> LDS scan -> dense LDS staging -> contiguous
// per-bucket flush. One global atomic per (block,bucket), coalesced u32 runs.
// Payload packed: bits 0..16 = t, bits 17..24 = s&255.
__global__ __launch_bounds__(SC_THREADS) void bucket_scatter(const int* __restrict__ ei,
                                                             int* __restrict__ bcnt,
                                                             unsigned int* __restrict__ bbuf) {
    __shared__ int h[NBK];          // hist -> cursors
    __shared__ int lofs[NBK];       // local exclusive offsets
    __shared__ int gbase[NBK];      // global base per bucket
    __shared__ int wsum[SC_THREADS / 64];
    __shared__ unsigned int stage[SC_CHUNK];

    const int tid = threadIdx.x;
    const int lane = tid & 63;
    const int wid = tid >> 6;
    const int e0 = blockIdx.x * SC_CHUNK;
    const int n = min(SC_CHUNK, N_EDGES - e0);

    for (int i = tid; i < NBK; i += SC_THREADS) h[i] = 0;
    __syncthreads();

    // phase 1: histogram of s
    for (int i = tid; i < n; i += SC_THREADS)
        atomicAdd(&h[ei[e0 + i] >> 8], 1);
    __syncthreads();

    // phase 2a: exclusive scan of h[0:NBK] (NBK=391 < 512)
    const int v = (tid < NBK) ? h[tid] : 0;
    int inc = v;
    #pragma unroll
    for (int d = 1; d < 64; d <<= 1) {
        int u = __shfl_up(inc, d);
        if (lane >= d) inc += u;
    }
    if (lane == 63) wsum[wid] = inc;
    __syncthreads();
    int woff = 0;
    for (int w = 0; w < wid; ++w) woff += wsum[w];
    if (tid < NBK) lofs[tid] = woff + inc - v;
    // phase 2b: global base per bucket (one atomic per block per bucket)
    if (tid < NBK) gbase[tid] = (v > 0) ? atomicAdd(&bcnt[tid], v) : 0;
    __syncthreads();

    // reset cursors
    for (int i = tid; i < NBK; i += SC_THREADS) h[i] = 0;
    __syncthreads();

    // phase 3: dense placement into LDS staging
    for (int i = tid; i < n; i += SC_THREADS) {
        const int s = ei[e0 + i];
        const int t = ei[N_EDGES + e0 + i];
        const int bk = s >> 8;
        const int c = atomicAdd(&h[bk], 1);
        stage[lofs[bk] + c] = (unsigned int)t | ((unsigned int)(s & 255) << 17);
    }
    __syncthreads();

    // phase 4: flush contiguous runs, buckets distributed across waves
    for (int bk = wid; bk < NBK; bk += SC_THREADS / 64) {
        const int cnt = h[bk];
        const int lo = lofs[bk];
        unsigned int* dst = bbuf + (size_t)bk * BCAP + gbase[bk];
        for (int i = lane; i < cnt; i += 64) dst[i] = stage[lo + i];
    }
}

// ---------------- Fused CSR build: deg + off + sorted_t (1 block/bucket) ----
__global__ __launch_bounds__(256) void csr_build(const int* __restrict__ bcnt,
                                                 const unsigned int* __restrict__ bbuf,
                                                 int* __restrict__ deg,
                                                 int* __restrict__ off,
                                                 int* __restrict__ sorted_t) {
    __shared__ int h[256];
    __shared__ int lofs[256];
    __shared__ int wsum[4];
    __shared__ int sBase;

    const int tid = threadIdx.x;
    const int lane = tid & 63;
    const int wid = tid >> 6;
    const int bk = blockIdx.x;
    const int n = bcnt[bk];

    // bucket edge base = sum of bcnt[0..bk)
    int pre = 0;
    for (int i = tid; i < bk; i += 256) pre += bcnt[i];
    #pragma unroll
    for (int d = 1; d < 64; d <<= 1) pre += __shfl_xor(pre, d);
    if (lane == 0) wsum[wid] = pre;
    h[tid] = 0;
    __syncthreads();
    if (tid == 0) sBase = wsum[0] + wsum[1] + wsum[2] + wsum[3];
    __syncthreads();

    // histogram of s&255 within bucket
    const unsigned int* p = bbuf + (size_t)bk * BCAP;
    for (int i = tid; i < n; i += 256)
        atomicAdd(&h[p[i] >> 17], 1);
    __syncthreads();

    // exclusive scan of h[256]
    const int v = h[tid];
    int inc = v;
    #pragma unroll
    for (int d = 1; d < 64; d <<= 1) {
        int u = __shfl_up(inc, d);
        if (lane >= d) inc += u;
    }
    if (lane == 63) wsum[wid] = inc;
    __syncthreads();
    int woff = 0;
    for (int w = 0; w < wid; ++w) woff += wsum[w];
    const int exc = woff + inc - v;
    lofs[tid] = exc;
    const int node = bk * 256 + tid;
    if (node < N_NODES) { deg[node] = v; off[node] = sBase + exc; }
    __syncthreads();

    // reset cursors, then scatter within bucket (dest window L2-hot)
    h[tid] = 0;
    __syncthreads();
    int* dstbase = sorted_t + sBase;
    for (int i = tid; i < n; i += 256) {
        const unsigned int e = p[i];
        const int s8 = e >> 17;
        const int c = atomicAdd(&h[s8], 1);
        dstbase[lofs[s8] + c] = (int)(e & 0x1FFFFu);
    }
}

// ---------------- Fused per-node attention ----------------
// One wave per node; 4 edges per step. lane = eg*16 + q16. bf16 k/v.
__global__ __launch_bounds__(256) void node_pass(const float* __restrict__ q_arr,
                                                 const unsigned short* __restrict__ kv,
                                                 const int* __restrict__ off,
                                                 const int* __restrict__ deg,
                                                 const int* __restrict__ sorted_t,
                                                 float* __restrict__ out) {
    const int node = blockIdx.x * 4 + (threadIdx.x >> 6);
    const int lane = threadIdx.x & 63;
    if (node >= N_NODES) return;
    const int eg = lane >> 4;
    const int q16 = lane & 15;

    const int o = off[node];
    const int d = deg[node];

    const float4 qv = *(const float4*)(q_arr + (size_t)node * 64 + q16 * 4);
    const float NEG_INF = -__builtin_inff();
    float m = NEG_INF;
    float l = 0.f;
    float4 acc = make_float4(0.f, 0.f, 0.f, 0.f);

    for (int base = 0; base < d; base += 64) {
        const int nb = min(64, d - base);
        int tb = (base + lane < d) ? sorted_t[o + base + lane] : 0;
        for (int j4 = 0; j4 < nb; j4 += 4) {
            const int idx = j4 + eg;
            const int t = __shfl(tb, idx);
            const unsigned short* kp = kv + (size_t)t * 128;
            const uint2 ku = *(const uint2*)(kp + q16 * 4);
            const uint2 vu = *(const uint2*)(kp + 64 + q16 * 4);
            const float k0 = __uint_as_float(ku.x << 16);
            const float k1 = __uint_as_float(ku.x & 0xffff0000u);
            const float k2 = __uint_as_float(ku.y << 16);
            const float k3 = __uint_as_float(ku.y & 0xffff0000u);
            float p = qv.x * k0 + qv.y * k1 + qv.z * k2 + qv.w * k3;
            p += __shfl_xor(p, 1);
            p += __shfl_xor(p, 2);             // per-head dot within quad
            p = (idx < nb) ? p : NEG_INF;      // mask invalid edge slots
            float pm = fmaxf(p, __shfl_xor(p, 16));
            pm = fmaxf(pm, __shfl_xor(pm, 32));   // max over the 4 edges
            const float nm = fmaxf(m, pm);
            const float sc = __expf(m - nm);   // eg-uniform
            const float ex = __expf(p - nm);   // 0 for invalid slots
            const float v0 = __uint_as_float(vu.x << 16);
            const float v1 = __uint_as_float(vu.x & 0xffff0000u);
            const float v2 = __uint_as_float(vu.y << 16);
            const float v3 = __uint_as_float(vu.y & 0xffff0000u);
            l = l * sc + ex;
            acc.x = acc.x * sc + ex * v0;
            acc.y = acc.y * sc + ex * v1;
            acc.z = acc.z * sc + ex * v2;
            acc.w = acc.w * sc + ex * v3;
            m = nm;
        }
    }
    l += __shfl_xor(l, 16);  l += __shfl_xor(l, 32);
    acc.x += __shfl_xor(acc.x, 16);  acc.x += __shfl_xor(acc.x, 32);
    acc.y += __shfl_xor(acc.y, 16);  acc.y += __shfl_xor(acc.y, 32);
    acc.z += __shfl_xor(acc.z, 16);  acc.z += __shfl_xor(acc.z, 32);
    acc.w += __shfl_xor(acc.w, 16);  acc.w += __shfl_xor(acc.w, 32);

    if (eg == 0) {
        const float inv = 1.f / (l + EPS);
        float4 r = make_float4(acc.x * inv, acc.y * inv, acc.z * inv, acc.w * inv);
        *(float4*)(out + (size_t)node * DIM + q16 * 4) = r;
    }
}

extern "C" void kernel_launch(void* const* d_in, const int* in_sizes, int n_in,
                              void* d_out, int out_size, void* d_ws, size_t ws_size,
                              hipStream_t stream) {
    const float* x = (const float*)d_in[0];
    const float* W = (const float*)d_in[1];
    const float* b = (const float*)d_in[2];
    const int*   ei = (const int*)d_in[3];   // (2, E): [0:E]=src, [E:2E]=tgt
    float* out = (float*)d_out;

    // workspace: q_arr 25.6MB | kv 25.6MB | bbuf 12.8MB | sorted_t 6.4MB | deg | off | bcnt
    float* q_arr = (float*)d_ws;
    unsigned short* kv = (unsigned short*)(q_arr + (size_t)N_NODES * 64);
    unsigned int* bbuf = (unsigned int*)(kv + (size_t)N_NODES * 128);
    int* sorted_t = (int*)(bbuf + (size_t)NBK * BCAP);
    int* deg      = sorted_t + N_EDGES;
    int* off      = deg + N_NODES;
    int* bcnt     = off + N_NODES;

    qkv_proj<<<QBLOCKS, 192, 0, stream>>>(x, W, b, q_arr, kv, bcnt);
    bucket_scatter<<<SC_BLOCKS, SC_THREADS, 0, stream>>>(ei, bcnt, bbuf);
    csr_build<<<NBK, 256, 0, stream>>>(bcnt, bbuf, deg, off, sorted_t);
    node_pass<<<(N_NODES + 3) / 4, 256, 0, stream>>>(q_arr, kv, off, deg, sorted_t, out);
}

// Round 8
// 151.261 us; speedup vs baseline: 40.6461x; 1.0301x over previous
//
#include <hip/hip_runtime.h>

// SelfAttentionBlock: graph transformer attention
// N=100000 nodes, E=1600000 edges, DIM=64, H=4 heads, d=16
constexpr int N_NODES = 100000;
constexpr int N_EDGES = 1600000;
constexpr int DIM = 64;
constexpr float QK_SCALE = 0.25f;   // 16^-0.5
constexpr float EPS = 1e-16f;

constexpr int QNB = 16;                       // nodes per qkv block
constexpr int QBLOCKS = N_NODES / QNB;        // 6250 (exact)

// bucket sort: bucket = s>>8 (256 nodes each)
constexpr int NBK = (N_NODES + 255) / 256;    // 391
constexpr int BCAP = 8192;                    // u32/bucket: mean 4092 -> huge headroom
constexpr int SC_CHUNK = 8192;                // edges per scatter block
constexpr int SC_THREADS = 512;
constexpr int SC_BLOCKS = (N_EDGES + SC_CHUNK - 1) / SC_CHUNK;  // 196

__device__ __forceinline__ unsigned short f32_to_bf16_rne(float f) {
    unsigned int u = __float_as_uint(f);
    u += 0x7fffu + ((u >> 16) & 1u);          // round-to-nearest-even
    return (unsigned short)(u >> 16);
}

// ---------------- K0: qkv projection (register-tiled) + bcnt zeroing --------
// kv row layout is INTERLEAVED per 4-dim chunk: [k0..3 v0..3 k4..7 v4..7 ...]
// so node_pass fetches k-pair+v-pair for its 4 dims in ONE uint4 load.
__global__ __launch_bounds__(192) void qkv_proj(const float* __restrict__ x,
                                                const float* __restrict__ W,
                                                const float* __restrict__ b,
                                                float* __restrict__ q_arr,
                                                unsigned short* __restrict__ kv,
                                                int* __restrict__ bcnt) {
    const int j = threadIdx.x;
    if (blockIdx.x == 0)                       // zero bcnt for the scatter kernel
        for (int i = j; i < NBK; i += 192) bcnt[i] = 0;

    const int n0 = blockIdx.x * QNB;
    const float bj = b[j];
    float acc[QNB];
    #pragma unroll
    for (int i = 0; i < QNB; ++i) acc[i] = bj;
    const float* xb = x + (size_t)n0 * DIM;
    #pragma unroll
    for (int k0 = 0; k0 < DIM; k0 += 4) {
        const float w0 = W[(k0 + 0) * 192 + j];
        const float w1 = W[(k0 + 1) * 192 + j];
        const float w2 = W[(k0 + 2) * 192 + j];
        const float w3 = W[(k0 + 3) * 192 + j];
        #pragma unroll
        for (int i = 0; i < QNB; ++i) {
            const float4 xv = *(const float4*)(xb + i * DIM + k0);
            acc[i] = fmaf(xv.x, w0, acc[i]);
            acc[i] = fmaf(xv.y, w1, acc[i]);
            acc[i] = fmaf(xv.z, w2, acc[i]);
            acc[i] = fmaf(xv.w, w3, acc[i]);
        }
    }
    if (j < 64) {
        #pragma unroll
        for (int i = 0; i < QNB; ++i)
            q_arr[(size_t)(n0 + i) * 64 + j] = acc[i] * QK_SCALE;
    } else {
        const int jj = j - 64;                 // 0..127: k dims 0..63, v dims 64..127
        const int pos = (jj < 64) ? ((jj >> 2) * 8 + (jj & 3))
                                  : (((jj - 64) >> 2) * 8 + 4 + ((jj - 64) & 3));
        #pragma unroll
        for (int i = 0; i < QNB; ++i)
            kv[(size_t)(n0 + i) * 128 + pos] = f32_to_bf16_rne(acc[i]);
    }
}

// ---------------- Bucket scatter with LDS dense staging ----------------
// Payload packed: bits 0..16 = t, bits 17..24 = s&255.
__global__ __launch_bounds__(SC_THREADS) void bucket_scatter(const int* __restrict__ ei,
                                                             int* __restrict__ bcnt,
                                                             unsigned int* __restrict__ bbuf) {
    __shared__ int h[NBK];          // hist -> cursors
    __shared__ int lofs[NBK];       // local exclusive offsets
    __shared__ int gbase[NBK];      // global base per bucket
    __shared__ int wsum[SC_THREADS / 64];
    __shared__ unsigned int stage[SC_CHUNK];

    const int tid = threadIdx.x;
    const int lane = tid & 63;
    const int wid = tid >> 6;
    const int e0 = blockIdx.x * SC_CHUNK;
    const int n = min(SC_CHUNK, N_EDGES - e0);

    for (int i = tid; i < NBK; i += SC_THREADS) h[i] = 0;
    __syncthreads();

    for (int i = tid; i < n; i += SC_THREADS)
        atomicAdd(&h[ei[e0 + i] >> 8], 1);
    __syncthreads();

    const int v = (tid < NBK) ? h[tid] : 0;
    int inc = v;
    #pragma unroll
    for (int d = 1; d < 64; d <<= 1) {
        int u = __shfl_up(inc, d);
        if (lane >= d) inc += u;
    }
    if (lane == 63) wsum[wid] = inc;
    __syncthreads();
    int woff = 0;
    for (int w = 0; w < wid; ++w) woff += wsum[w];
    if (tid < NBK) lofs[tid] = woff + inc - v;
    if (tid < NBK) gbase[tid] = (v > 0) ? atomicAdd(&bcnt[tid], v) : 0;
    __syncthreads();

    for (int i = tid; i < NBK; i += SC_THREADS) h[i] = 0;
    __syncthreads();

    for (int i = tid; i < n; i += SC_THREADS) {
        const int s = ei[e0 + i];
        const int t = ei[N_EDGES + e0 + i];
        const int bk = s >> 8;
        const int c = atomicAdd(&h[bk], 1);
        stage[lofs[bk] + c] = (unsigned int)t | ((unsigned int)(s & 255) << 17);
    }
    __syncthreads();

    for (int bk = wid; bk < NBK; bk += SC_THREADS / 64) {
        const int cnt = h[bk];
        const int lo = lofs[bk];
        unsigned int* dst = bbuf + (size_t)bk * BCAP + gbase[bk];
        for (int i = lane; i < cnt; i += 64) dst[i] = stage[lo + i];
    }
}

// ---------------- Fused CSR build: deg + off + sorted_t (1 block/bucket) ----
__global__ __launch_bounds__(256) void csr_build(const int* __restrict__ bcnt,
                                                 const unsigned int* __restrict__ bbuf,
                                                 int* __restrict__ deg,
                                                 int* __restrict__ off,
                                                 int* __restrict__ sorted_t) {
    __shared__ int h[256];
    __shared__ int lofs[256];
    __shared__ int wsum[4];
    __shared__ int sBase;

    const int tid = threadIdx.x;
    const int lane = tid & 63;
    const int wid = tid >> 6;
    const int bk = blockIdx.x;
    const int n = bcnt[bk];

    int pre = 0;
    for (int i = tid; i < bk; i += 256) pre += bcnt[i];
    #pragma unroll
    for (int d = 1; d < 64; d <<= 1) pre += __shfl_xor(pre, d);
    if (lane == 0) wsum[wid] = pre;
    h[tid] = 0;
    __syncthreads();
    if (tid == 0) sBase = wsum[0] + wsum[1] + wsum[2] + wsum[3];
    __syncthreads();

    const unsigned int* p = bbuf + (size_t)bk * BCAP;
    for (int i = tid; i < n; i += 256)
        atomicAdd(&h[p[i] >> 17], 1);
    __syncthreads();

    const int v = h[tid];
    int inc = v;
    #pragma unroll
    for (int d = 1; d < 64; d <<= 1) {
        int u = __shfl_up(inc, d);
        if (lane >= d) inc += u;
    }
    if (lane == 63) wsum[wid] = inc;
    __syncthreads();
    int woff = 0;
    for (int w = 0; w < wid; ++w) woff += wsum[w];
    const int exc = woff + inc - v;
    lofs[tid] = exc;
    const int node = bk * 256 + tid;
    if (node < N_NODES) { deg[node] = v; off[node] = sBase + exc; }
    __syncthreads();

    h[tid] = 0;
    __syncthreads();
    int* dstbase = sorted_t + sBase;
    for (int i = tid; i < n; i += 256) {
        const unsigned int e = p[i];
        const int s8 = e >> 17;
        const int c = atomicAdd(&h[s8], 1);
        dstbase[lofs[s8] + c] = (int)(e & 0x1FFFFu);
    }
}

// ---------------- Fused per-node attention ----------------
// One wave per node; 8 edges per step (2 per eg slot). lane = eg*16 + q16.
// Interleaved bf16 kv row: one uint4 load = k-pair + v-pair for lane's 4 dims.
// Conditional rescale: skip the sc-exp + 5 mults when no head's max grew (exact:
// skipped path is multiply-by-exp(0)=1).
__global__ __launch_bounds__(256) void node_pass(const float* __restrict__ q_arr,
                                                 const unsigned short* __restrict__ kv,
                                                 const int* __restrict__ off,
                                                 const int* __restrict__ deg,
                                                 const int* __restrict__ sorted_t,
                                                 float* __restrict__ out) {
    const int node = blockIdx.x * 4 + (threadIdx.x >> 6);
    const int lane = threadIdx.x & 63;
    if (node >= N_NODES) return;
    const int eg = lane >> 4;
    const int q16 = lane & 15;

    const int o = off[node];
    const int d = deg[node];

    const float4 qv = *(const float4*)(q_arr + (size_t)node * 64 + q16 * 4);
    const float NEG_INF = -__builtin_inff();
    float m = NEG_INF;
    float l = 0.f;
    float4 acc = make_float4(0.f, 0.f, 0.f, 0.f);

    for (int base = 0; base < d; base += 64) {
        const int nb = min(64, d - base);
        int tb = (base + lane < d) ? sorted_t[o + base + lane] : 0;
        for (int j8 = 0; j8 < nb; j8 += 8) {
            const int ia = j8 + eg;
            const int ib = j8 + 4 + eg;
            const int ta = __shfl(tb, ia);
            const int tc = __shfl(tb, ib);     // invalid slots broadcast tb=0: safe row
            const uint4 A = *(const uint4*)(kv + (size_t)ta * 128 + q16 * 8);
            const uint4 B = *(const uint4*)(kv + (size_t)tc * 128 + q16 * 8);
            // k in .x/.y, v in .z/.w (interleaved layout)
            float pa = qv.x * __uint_as_float(A.x << 16)
                     + qv.y * __uint_as_float(A.x & 0xffff0000u)
                     + qv.z * __uint_as_float(A.y << 16)
                     + qv.w * __uint_as_float(A.y & 0xffff0000u);
            float pb = qv.x * __uint_as_float(B.x << 16)
                     + qv.y * __uint_as_float(B.x & 0xffff0000u)
                     + qv.z * __uint_as_float(B.y << 16)
                     + qv.w * __uint_as_float(B.y & 0xffff0000u);
            pa += __shfl_xor(pa, 1);  pb += __shfl_xor(pb, 1);
            pa += __shfl_xor(pa, 2);  pb += __shfl_xor(pb, 2);   // per-head dots
            pa = (ia < nb) ? pa : NEG_INF;
            pb = (ib < nb) ? pb : NEG_INF;
            float pm = fmaxf(pa, pb);
            pm = fmaxf(pm, __shfl_xor(pm, 16));
            pm = fmaxf(pm, __shfl_xor(pm, 32));   // per-head max over the 8 edges
            if (__any(pm > m)) {
                const float nm = fmaxf(m, pm);    // per-head
                const float sc = __expf(m - nm);  // ==1 for heads that didn't grow
                l *= sc;
                acc.x *= sc; acc.y *= sc; acc.z *= sc; acc.w *= sc;
                m = nm;
            }
            const float ea = __expf(pa - m);      // 0 for masked slots
            const float eb = __expf(pb - m);
            l += ea + eb;
            acc.x = fmaf(ea, __uint_as_float(A.z << 16),
                    fmaf(eb, __uint_as_float(B.z << 16),         acc.x));
            acc.y = fmaf(ea, __uint_as_float(A.z & 0xffff0000u),
                    fmaf(eb, __uint_as_float(B.z & 0xffff0000u), acc.y));
            acc.z = fmaf(ea, __uint_as_float(A.w << 16),
                    fmaf(eb, __uint_as_float(B.w << 16),         acc.z));
            acc.w = fmaf(ea, __uint_as_float(A.w & 0xffff0000u),
                    fmaf(eb, __uint_as_float(B.w & 0xffff0000u), acc.w));
        }
    }
    l += __shfl_xor(l, 16);  l += __shfl_xor(l, 32);
    acc.x += __shfl_xor(acc.x, 16);  acc.x += __shfl_xor(acc.x, 32);
    acc.y += __shfl_xor(acc.y, 16);  acc.y += __shfl_xor(acc.y, 32);
    acc.z += __shfl_xor(acc.z, 16);  acc.z += __shfl_xor(acc.z, 32);
    acc.w += __shfl_xor(acc.w, 16);  acc.w += __shfl_xor(acc.w, 32);

    if (eg == 0) {
        const float inv = 1.f / (l + EPS);
        float4 r = make_float4(acc.x * inv, acc.y * inv, acc.z * inv, acc.w * inv);
        *(float4*)(out + (size_t)node * DIM + q16 * 4) = r;
    }
}

extern "C" void kernel_launch(void* const* d_in, const int* in_sizes, int n_in,
                              void* d_out, int out_size, void* d_ws, size_t ws_size,
                              hipStream_t stream) {
    const float* x = (const float*)d_in[0];
    const float* W = (const float*)d_in[1];
    const float* b = (const float*)d_in[2];
    const int*   ei = (const int*)d_in[3];   // (2, E): [0:E]=src, [E:2E]=tgt
    float* out = (float*)d_out;

    // workspace: q_arr 25.6MB | kv 25.6MB | bbuf 12.8MB | sorted_t 6.4MB | deg | off | bcnt
    float* q_arr = (float*)d_ws;
    unsigned short* kv = (unsigned short*)(q_arr + (size_t)N_NODES * 64);
    unsigned int* bbuf = (unsigned int*)(kv + (size_t)N_NODES * 128);
    int* sorted_t = (int*)(bbuf + (size_t)NBK * BCAP);
    int* deg      = sorted_t + N_EDGES;
    int* off      = deg + N_NODES;
    int* bcnt     = off + N_NODES;

    qkv_proj<<<QBLOCKS, 192, 0, stream>>>(x, W, b, q_arr, kv, bcnt);
    bucket_scatter<<<SC_BLOCKS, SC_THREADS, 0, stream>>>(ei, bcnt, bbuf);
    csr_build<<<NBK, 256, 0, stream>>>(bcnt, bbuf, deg, off, sorted_t);
    node_pass<<<(N_NODES + 3) / 4, 256, 0, stream>>>(q_arr, kv, off, deg, sorted_t, out);
}

// Round 9
// 139.475 us; speedup vs baseline: 44.0810x; 1.0845x over previous
//
#include <hip/hip_runtime.h>

// SelfAttentionBlock: graph transformer attention
// N=100000 nodes, E=1600000 edges, DIM=64, H=4 heads, d=16
constexpr int N_NODES = 100000;
constexpr int N_EDGES = 1600000;
constexpr int DIM = 64;
constexpr float QK_SCALE = 0.25f;   // 16^-0.5
constexpr float EPS = 1e-16f;

// bucket sort: bucket = s>>8 (256 nodes each)
constexpr int NBK = (N_NODES + 255) / 256;    // 391
constexpr int BCAP = 8192;                    // u32/bucket: mean 4092 -> huge headroom
constexpr int SC_CHUNK = 8192;                // edges per scatter block
constexpr int SC_THREADS = 512;
constexpr int SC_BLOCKS = (N_EDGES + SC_CHUNK - 1) / SC_CHUNK;  // 196

typedef __attribute__((ext_vector_type(8))) short short8;   // 8 bf16 (4 VGPR)
typedef __attribute__((ext_vector_type(4))) float f32x4;

__device__ __forceinline__ unsigned short f32_to_bf16_rne(float f) {
    unsigned int u = __float_as_uint(f);
    u += 0x7fffu + ((u >> 16) & 1u);          // round-to-nearest-even
    return (unsigned short)(u >> 16);
}

// permuted output column jp -> original W column.
// jp 0..63: q cols. jp 64..191: interleaved kv layout [k0..3 v0..3 k4..7 ...]
__device__ __forceinline__ int orig_col(int jp) {
    if (jp < 64) return jp;
    const int p = jp - 64;
    const int chunk = p >> 3, w = p & 7;
    return (w < 4) ? (64 + chunk * 4 + w) : (128 + chunk * 4 + (w - 4));
}

// ---------------- prep: Wbt[jp][k] bf16 (permuted cols, q cols pre-scaled),
// bias bb[jp] f32, and bcnt zeroing. One tiny block.
__global__ __launch_bounds__(192) void prep_w(const float* __restrict__ W,
                                              const float* __restrict__ b,
                                              unsigned short* __restrict__ Wbt,
                                              float* __restrict__ bb,
                                              int* __restrict__ bcnt) {
    const int jp = threadIdx.x;
    const int oc = orig_col(jp);
    const float sc = (jp < 64) ? QK_SCALE : 1.f;   // 0.25 = pow2, exact in bf16
    for (int k = 0; k < DIM; ++k)
        Wbt[jp * DIM + k] = f32_to_bf16_rne(W[k * 192 + oc] * sc);
    bb[jp] = b[oc] * sc;
    for (int i = jp; i < NBK; i += 192) bcnt[i] = 0;
}

// ---------------- qkv projection via MFMA ----------------
// Wave = 16 nodes x 192 cols; 12 col-tiles x 2 K-halves = 24 mfma.
// A frag: lane holds x[row=l&15][k=(l>>4)*8+i]  (8 consecutive f32 -> bf16)
// B frag: lane holds Wbt[col=l&15][k=(l>>4)*8+i] (16B contiguous)
// D: col = l&15, row = (l>>4)*4 + reg  (m89-verified)
__global__ __launch_bounds__(256) void qkv_mfma(const float* __restrict__ x,
                                                const unsigned short* __restrict__ Wbt,
                                                const float* __restrict__ bb,
                                                float* __restrict__ q_arr,
                                                unsigned short* __restrict__ kv) {
    const int lane = threadIdx.x & 63;
    const int wid = threadIdx.x >> 6;
    const int n0 = blockIdx.x * 64 + wid * 16;     // wave's first node
    if (n0 >= N_NODES) return;                     // wave-uniform
    const int row = lane & 15;
    const int kg = lane >> 4;

    const int nidx = min(n0 + row, N_NODES - 1);   // clamp for tail block loads
    const float* xr = x + (size_t)nidx * DIM + kg * 8;
    short8 a0, a1;
    {
        const float4 u0 = *(const float4*)(xr);
        const float4 u1 = *(const float4*)(xr + 4);
        const float4 u2 = *(const float4*)(xr + 32);
        const float4 u3 = *(const float4*)(xr + 36);
        a0[0] = (short)f32_to_bf16_rne(u0.x); a0[1] = (short)f32_to_bf16_rne(u0.y);
        a0[2] = (short)f32_to_bf16_rne(u0.z); a0[3] = (short)f32_to_bf16_rne(u0.w);
        a0[4] = (short)f32_to_bf16_rne(u1.x); a0[5] = (short)f32_to_bf16_rne(u1.y);
        a0[6] = (short)f32_to_bf16_rne(u1.z); a0[7] = (short)f32_to_bf16_rne(u1.w);
        a1[0] = (short)f32_to_bf16_rne(u2.x); a1[1] = (short)f32_to_bf16_rne(u2.y);
        a1[2] = (short)f32_to_bf16_rne(u2.z); a1[3] = (short)f32_to_bf16_rne(u2.w);
        a1[4] = (short)f32_to_bf16_rne(u3.x); a1[5] = (short)f32_to_bf16_rne(u3.y);
        a1[6] = (short)f32_to_bf16_rne(u3.z); a1[7] = (short)f32_to_bf16_rne(u3.w);
    }

    #pragma unroll
    for (int ct = 0; ct < 12; ++ct) {
        const int c0 = ct * 16;
        const float bias = bb[c0 + row];           // D col == lane&15
        f32x4 acc = {bias, bias, bias, bias};
        const short8 b0 = *(const short8*)(Wbt + (c0 + row) * DIM + kg * 8);
        const short8 b1 = *(const short8*)(Wbt + (c0 + row) * DIM + kg * 8 + 32);
        acc = __builtin_amdgcn_mfma_f32_16x16x32_bf16(a0, b0, acc, 0, 0, 0);
        acc = __builtin_amdgcn_mfma_f32_16x16x32_bf16(a1, b1, acc, 0, 0, 0);

        const int colg = c0 + row;                 // permuted global col
        #pragma unroll
        for (int r = 0; r < 4; ++r) {
            const int node = n0 + kg * 4 + r;
            if (node < N_NODES) {
                if (c0 < 64) q_arr[(size_t)node * 64 + colg] = acc[r];
                else kv[(size_t)node * 128 + (colg - 64)] = f32_to_bf16_rne(acc[r]);
            }
        }
    }
}

// ---------------- Bucket scatter with LDS dense staging ----------------
// Payload packed: bits 0..16 = t, bits 17..24 = s&255.
__global__ __launch_bounds__(SC_THREADS) void bucket_scatter(const int* __restrict__ ei,
                                                             int* __restrict__ bcnt,
                                                             unsigned int* __restrict__ bbuf) {
    __shared__ int h[NBK];          // hist -> cursors
    __shared__ int lofs[NBK];       // local exclusive offsets
    __shared__ int gbase[NBK];      // global base per bucket
    __shared__ int wsum[SC_THREADS / 64];
    __shared__ unsigned int stage[SC_CHUNK];

    const int tid = threadIdx.x;
    const int lane = tid & 63;
    const int wid = tid >> 6;
    const int e0 = blockIdx.x * SC_CHUNK;
    const int n = min(SC_CHUNK, N_EDGES - e0);

    for (int i = tid; i < NBK; i += SC_THREADS) h[i] = 0;
    __syncthreads();

    for (int i = tid; i < n; i += SC_THREADS)
        atomicAdd(&h[ei[e0 + i] >> 8], 1);
    __syncthreads();

    const int v = (tid < NBK) ? h[tid] : 0;
    int inc = v;
    #pragma unroll
    for (int d = 1; d < 64; d <<= 1) {
        int u = __shfl_up(inc, d);
        if (lane >= d) inc += u;
    }
    if (lane == 63) wsum[wid] = inc;
    __syncthreads();
    int woff = 0;
    for (int w = 0; w < wid; ++w) woff += wsum[w];
    if (tid < NBK) lofs[tid] = woff + inc - v;
    if (tid < NBK) gbase[tid] = (v > 0) ? atomicAdd(&bcnt[tid], v) : 0;
    __syncthreads();

    for (int i = tid; i < NBK; i += SC_THREADS) h[i] = 0;
    __syncthreads();

    for (int i = tid; i < n; i += SC_THREADS) {
        const int s = ei[e0 + i];
        const int t = ei[N_EDGES + e0 + i];
        const int bk = s >> 8;
        const int c = atomicAdd(&h[bk], 1);
        stage[lofs[bk] + c] = (unsigned int)t | ((unsigned int)(s & 255) << 17);
    }
    __syncthreads();

    for (int bk = wid; bk < NBK; bk += SC_THREADS / 64) {
        const int cnt = h[bk];
        const int lo = lofs[bk];
        unsigned int* dst = bbuf + (size_t)bk * BCAP + gbase[bk];
        for (int i = lane; i < cnt; i += 64) dst[i] = stage[lo + i];
    }
}

// ---------------- Fused CSR build: deg + off + sorted_t (1 block/bucket) ----
__global__ __launch_bounds__(256) void csr_build(const int* __restrict__ bcnt,
                                                 const unsigned int* __restrict__ bbuf,
                                                 int* __restrict__ deg,
                                                 int* __restrict__ off,
                                                 int* __restrict__ sorted_t) {
    __shared__ int h[256];
    __shared__ int lofs[256];
    __shared__ int wsum[4];
    __shared__ int sBase;

    const int tid = threadIdx.x;
    const int lane = tid & 63;
    const int wid = tid >> 6;
    const int bk = blockIdx.x;
    const int n = bcnt[bk];

    int pre = 0;
    for (int i = tid; i < bk; i += 256) pre += bcnt[i];
    #pragma unroll
    for (int d = 1; d < 64; d <<= 1) pre += __shfl_xor(pre, d);
    if (lane == 0) wsum[wid] = pre;
    h[tid] = 0;
    __syncthreads();
    if (tid == 0) sBase = wsum[0] + wsum[1] + wsum[2] + wsum[3];
    __syncthreads();

    const unsigned int* p = bbuf + (size_t)bk * BCAP;
    for (int i = tid; i < n; i += 256)
        atomicAdd(&h[p[i] >> 17], 1);
    __syncthreads();

    const int v = h[tid];
    int inc = v;
    #pragma unroll
    for (int d = 1; d < 64; d <<= 1) {
        int u = __shfl_up(inc, d);
        if (lane >= d) inc += u;
    }
    if (lane == 63) wsum[wid] = inc;
    __syncthreads();
    int woff = 0;
    for (int w = 0; w < wid; ++w) woff += wsum[w];
    const int exc = woff + inc - v;
    lofs[tid] = exc;
    const int node = bk * 256 + tid;
    if (node < N_NODES) { deg[node] = v; off[node] = sBase + exc; }
    __syncthreads();

    h[tid] = 0;
    __syncthreads();
    int* dstbase = sorted_t + sBase;
    for (int i = tid; i < n; i += 256) {
        const unsigned int e = p[i];
        const int s8 = e >> 17;
        const int c = atomicAdd(&h[s8], 1);
        dstbase[lofs[s8] + c] = (int)(e & 0x1FFFFu);
    }
}

// ---------------- Fused per-node attention ----------------
// One wave per node; 8 edges per step (2 per eg slot). lane = eg*16 + q16.
// Interleaved bf16 kv row: one uint4 load = k-pair + v-pair for lane's 4 dims.
__global__ __launch_bounds__(256) void node_pass(const float* __restrict__ q_arr,
                                                 const unsigned short* __restrict__ kv,
                                                 const int* __restrict__ off,
                                                 const int* __restrict__ deg,
                                                 const int* __restrict__ sorted_t,
                                                 float* __restrict__ out) {
    const int node = blockIdx.x * 4 + (threadIdx.x >> 6);
    const int lane = threadIdx.x & 63;
    if (node >= N_NODES) return;
    const int eg = lane >> 4;
    const int q16 = lane & 15;

    const int o = off[node];
    const int d = deg[node];

    const float4 qv = *(const float4*)(q_arr + (size_t)node * 64 + q16 * 4);
    const float NEG_INF = -__builtin_inff();
    float m = NEG_INF;
    float l = 0.f;
    float4 acc = make_float4(0.f, 0.f, 0.f, 0.f);

    for (int base = 0; base < d; base += 64) {
        const int nb = min(64, d - base);
        int tb = (base + lane < d) ? sorted_t[o + base + lane] : 0;
        for (int j8 = 0; j8 < nb; j8 += 8) {
            const int ia = j8 + eg;
            const int ib = j8 + 4 + eg;
            const int ta = __shfl(tb, ia);
            const int tc = __shfl(tb, ib);     // invalid slots broadcast tb=0: safe row
            const uint4 A = *(const uint4*)(kv + (size_t)ta * 128 + q16 * 8);
            const uint4 B = *(const uint4*)(kv + (size_t)tc * 128 + q16 * 8);
            float pa = qv.x * __uint_as_float(A.x << 16)
                     + qv.y * __uint_as_float(A.x & 0xffff0000u)
                     + qv.z * __uint_as_float(A.y << 16)
                     + qv.w * __uint_as_float(A.y & 0xffff0000u);
            float pb = qv.x * __uint_as_float(B.x << 16)
                     + qv.y * __uint_as_float(B.x & 0xffff0000u)
                     + qv.z * __uint_as_float(B.y << 16)
                     + qv.w * __uint_as_float(B.y & 0xffff0000u);
            pa += __shfl_xor(pa, 1);  pb += __shfl_xor(pb, 1);
            pa += __shfl_xor(pa, 2);  pb += __shfl_xor(pb, 2);   // per-head dots
            pa = (ia < nb) ? pa : NEG_INF;
            pb = (ib < nb) ? pb : NEG_INF;
            float pm = fmaxf(pa, pb);
            pm = fmaxf(pm, __shfl_xor(pm, 16));
            pm = fmaxf(pm, __shfl_xor(pm, 32));   // per-head max over the 8 edges
            if (__any(pm > m)) {
                const float nm = fmaxf(m, pm);
                const float sc = __expf(m - nm);
                l *= sc;
                acc.x *= sc; acc.y *= sc; acc.z *= sc; acc.w *= sc;
                m = nm;
            }
            const float ea = __expf(pa - m);      // 0 for masked slots
            const float eb = __expf(pb - m);
            l += ea + eb;
            acc.x = fmaf(ea, __uint_as_float(A.z << 16),
                    fmaf(eb, __uint_as_float(B.z << 16),         acc.x));
            acc.y = fmaf(ea, __uint_as_float(A.z & 0xffff0000u),
                    fmaf(eb, __uint_as_float(B.z & 0xffff0000u), acc.y));
            acc.z = fmaf(ea, __uint_as_float(A.w << 16),
                    fmaf(eb, __uint_as_float(B.w << 16),         acc.z));
            acc.w = fmaf(ea, __uint_as_float(A.w & 0xffff0000u),
                    fmaf(eb, __uint_as_float(B.w & 0xffff0000u), acc.w));
        }
    }
    l += __shfl_xor(l, 16);  l += __shfl_xor(l, 32);
    acc.x += __shfl_xor(acc.x, 16);  acc.x += __shfl_xor(acc.x, 32);
    acc.y += __shfl_xor(acc.y, 16);  acc.y += __shfl_xor(acc.y, 32);
    acc.z += __shfl_xor(acc.z, 16);  acc.z += __shfl_xor(acc.z, 32);
    acc.w += __shfl_xor(acc.w, 16);  acc.w += __shfl_xor(acc.w, 32);

    if (eg == 0) {
        const float inv = 1.f / (l + EPS);
        float4 r = make_float4(acc.x * inv, acc.y * inv, acc.z * inv, acc.w * inv);
        *(float4*)(out + (size_t)node * DIM + q16 * 4) = r;
    }
}

extern "C" void kernel_launch(void* const* d_in, const int* in_sizes, int n_in,
                              void* d_out, int out_size, void* d_ws, size_t ws_size,
                              hipStream_t stream) {
    const float* x = (const float*)d_in[0];
    const float* W = (const float*)d_in[1];
    const float* b = (const float*)d_in[2];
    const int*   ei = (const int*)d_in[3];   // (2, E): [0:E]=src, [E:2E]=tgt
    float* out = (float*)d_out;

    // workspace: q_arr 25.6MB | kv 25.6MB | bbuf 12.8MB | sorted_t 6.4MB |
    //            deg | off | bcnt | Wbt | bb
    float* q_arr = (float*)d_ws;
    unsigned short* kv = (unsigned short*)(q_arr + (size_t)N_NODES * 64);
    unsigned int* bbuf = (unsigned int*)(kv + (size_t)N_NODES * 128);
    int* sorted_t = (int*)(bbuf + (size_t)NBK * BCAP);
    int* deg      = sorted_t + N_EDGES;
    int* off      = deg + N_NODES;
    int* bcnt     = off + N_NODES;
    unsigned short* Wbt = (unsigned short*)(bcnt + NBK);   // 192*64 bf16
    float* bb     = (float*)(Wbt + 192 * DIM);             // 192 f32

    prep_w<<<1, 192, 0, stream>>>(W, b, Wbt, bb, bcnt);
    qkv_mfma<<<(N_NODES + 63) / 64, 256, 0, stream>>>(x, Wbt, bb, q_arr, kv);
    bucket_scatter<<<SC_BLOCKS, SC_THREADS, 0, stream>>>(ei, bcnt, bbuf);
    csr_build<<<NBK, 256, 0, stream>>>(bcnt, bbuf, deg, off, sorted_t);
    node_pass<<<(N_NODES + 3) / 4, 256, 0, stream>>>(q_arr, kv, off, deg, sorted_t, out);
}

// Round 10
// 135.136 us; speedup vs baseline: 45.4962x; 1.0321x over previous
//
#include <hip/hip_runtime.h>

// SelfAttentionBlock: graph transformer attention
// N=100000 nodes, E=1600000 edges, DIM=64, H=4 heads, d=16
constexpr int N_NODES = 100000;
constexpr int N_EDGES = 1600000;
constexpr int DIM = 64;
constexpr float QK_SCALE = 0.25f;   // 16^-0.5
constexpr float LOG2E = 1.4426950408889634f;
constexpr float EPS = 1e-16f;

// bucket sort: bucket = s>>8 (256 nodes each)
constexpr int NBK = (N_NODES + 255) / 256;    // 391
constexpr int BCAP = 8192;                    // u32/bucket: mean 4092 -> huge headroom
constexpr int SC_CHUNK = 8192;                // edges per scatter block
constexpr int SC_THREADS = 512;
constexpr int SC_BLOCKS = (N_EDGES + SC_CHUNK - 1) / SC_CHUNK;  // 196

typedef __attribute__((ext_vector_type(8))) short short8;   // 8 bf16 (4 VGPR)
typedef __attribute__((ext_vector_type(4))) float f32x4;

__device__ __forceinline__ unsigned short f32_to_bf16_rne(float f) {
    unsigned int u = __float_as_uint(f);
    u += 0x7fffu + ((u >> 16) & 1u);          // round-to-nearest-even
    return (unsigned short)(u >> 16);
}
__device__ __forceinline__ float bf_lo(unsigned int u) { return __uint_as_float(u << 16); }
__device__ __forceinline__ float bf_hi(unsigned int u) { return __uint_as_float(u & 0xffff0000u); }

// sum over 4-lane quad via DPP (quad_perm xor1 = 0xB1, xor2 = 0x4E) - pure VALU
__device__ __forceinline__ float qsum4(float p) {
    int a = __builtin_amdgcn_update_dpp(0, __float_as_int(p), 0xB1, 0xF, 0xF, true);
    p += __int_as_float(a);
    int c = __builtin_amdgcn_update_dpp(0, __float_as_int(p), 0x4E, 0xF, 0xF, true);
    p += __int_as_float(c);
    return p;
}

// permuted output column jp -> original W column.
// jp 0..63: q cols. jp 64..191: interleaved kv layout [k0..3 v0..3 k4..7 ...]
__device__ __forceinline__ int orig_col(int jp) {
    if (jp < 64) return jp;
    const int p = jp - 64;
    const int chunk = p >> 3, w = p & 7;
    return (w < 4) ? (64 + chunk * 4 + w) : (128 + chunk * 4 + (w - 4));
}

// ---------------- prep: Wbt[jp][k] bf16 (permuted cols; q cols scaled by
// QK_SCALE*log2e for exp2-domain softmax), bias bb[jp] f32, bcnt zeroing.
// 64 blocks (k = blockIdx) x 192 threads (jp) -> coalesced W row reads.
__global__ __launch_bounds__(192) void prep_w(const float* __restrict__ W,
                                              const float* __restrict__ b,
                                              unsigned short* __restrict__ Wbt,
                                              float* __restrict__ bb,
                                              int* __restrict__ bcnt) {
    const int jp = threadIdx.x;
    const int k = blockIdx.x;
    const int oc = orig_col(jp);
    const float sc = (jp < 64) ? QK_SCALE * LOG2E : 1.f;
    Wbt[jp * DIM + k] = f32_to_bf16_rne(W[k * 192 + oc] * sc);
    if (k == 0) {
        bb[jp] = b[oc] * sc;
        for (int i = jp; i < NBK; i += 192) bcnt[i] = 0;
    }
}

// ---------------- qkv projection via MFMA ----------------
// Wave = 16 nodes x 192 cols; 12 col-tiles x 2 K-halves = 24 mfma.
// Output: unified bf16 table qkv_t[node][192] = [q(64, log2-domain) | kv(128 interleaved)]
// Row = 384 B = 3 cache lines; q chunk = line 0, kv chunk = lines 1-2 (aligned).
__global__ __launch_bounds__(256) void qkv_mfma(const float* __restrict__ x,
                                                const unsigned short* __restrict__ Wbt,
                                                const float* __restrict__ bb,
                                                unsigned short* __restrict__ qkv_t) {
    const int lane = threadIdx.x & 63;
    const int wid = threadIdx.x >> 6;
    const int n0 = blockIdx.x * 64 + wid * 16;     // wave's first node
    if (n0 >= N_NODES) return;                     // wave-uniform
    const int row = lane & 15;
    const int kg = lane >> 4;

    const int nidx = min(n0 + row, N_NODES - 1);   // clamp for tail block loads
    const float* xr = x + (size_t)nidx * DIM + kg * 8;
    short8 a0, a1;
    {
        const float4 u0 = *(const float4*)(xr);
        const float4 u1 = *(const float4*)(xr + 4);
        const float4 u2 = *(const float4*)(xr + 32);
        const float4 u3 = *(const float4*)(xr + 36);
        a0[0] = (short)f32_to_bf16_rne(u0.x); a0[1] = (short)f32_to_bf16_rne(u0.y);
        a0[2] = (short)f32_to_bf16_rne(u0.z); a0[3] = (short)f32_to_bf16_rne(u0.w);
        a0[4] = (short)f32_to_bf16_rne(u1.x); a0[5] = (short)f32_to_bf16_rne(u1.y);
        a0[6] = (short)f32_to_bf16_rne(u1.z); a0[7] = (short)f32_to_bf16_rne(u1.w);
        a1[0] = (short)f32_to_bf16_rne(u2.x); a1[1] = (short)f32_to_bf16_rne(u2.y);
        a1[2] = (short)f32_to_bf16_rne(u2.z); a1[3] = (short)f32_to_bf16_rne(u2.w);
        a1[4] = (short)f32_to_bf16_rne(u3.x); a1[5] = (short)f32_to_bf16_rne(u3.y);
        a1[6] = (short)f32_to_bf16_rne(u3.z); a1[7] = (short)f32_to_bf16_rne(u3.w);
    }

    #pragma unroll
    for (int ct = 0; ct < 12; ++ct) {
        const int c0 = ct * 16;
        const float bias = bb[c0 + row];           // D col == lane&15
        f32x4 acc = {bias, bias, bias, bias};
        const short8 b0 = *(const short8*)(Wbt + (c0 + row) * DIM + kg * 8);
        const short8 b1 = *(const short8*)(Wbt + (c0 + row) * DIM + kg * 8 + 32);
        acc = __builtin_amdgcn_mfma_f32_16x16x32_bf16(a0, b0, acc, 0, 0, 0);
        acc = __builtin_amdgcn_mfma_f32_16x16x32_bf16(a1, b1, acc, 0, 0, 0);

        const int colg = c0 + row;                 // permuted global col
        #pragma unroll
        for (int r = 0; r < 4; ++r) {
            const int node = n0 + kg * 4 + r;
            if (node < N_NODES)
                qkv_t[(size_t)node * 192 + colg] = f32_to_bf16_rne(acc[r]);
        }
    }
}

// ---------------- Bucket scatter with LDS dense staging ----------------
// Payload packed: bits 0..16 = t, bits 17..24 = s&255.
__global__ __launch_bounds__(SC_THREADS) void bucket_scatter(const int* __restrict__ ei,
                                                             int* __restrict__ bcnt,
                                                             unsigned int* __restrict__ bbuf) {
    __shared__ int h[NBK];          // hist -> cursors
    __shared__ int lofs[NBK];       // local exclusive offsets
    __shared__ int gbase[NBK];      // global base per bucket
    __shared__ int wsum[SC_THREADS / 64];
    __shared__ unsigned int stage[SC_CHUNK];

    const int tid = threadIdx.x;
    const int lane = tid & 63;
    const int wid = tid >> 6;
    const int e0 = blockIdx.x * SC_CHUNK;
    const int n = min(SC_CHUNK, N_EDGES - e0);

    for (int i = tid; i < NBK; i += SC_THREADS) h[i] = 0;
    __syncthreads();

    for (int i = tid; i < n; i += SC_THREADS)
        atomicAdd(&h[ei[e0 + i] >> 8], 1);
    __syncthreads();

    const int v = (tid < NBK) ? h[tid] : 0;
    int inc = v;
    #pragma unroll
    for (int d = 1; d < 64; d <<= 1) {
        int u = __shfl_up(inc, d);
        if (lane >= d) inc += u;
    }
    if (lane == 63) wsum[wid] = inc;
    __syncthreads();
    int woff = 0;
    for (int w = 0; w < wid; ++w) woff += wsum[w];
    if (tid < NBK) lofs[tid] = woff + inc - v;
    if (tid < NBK) gbase[tid] = (v > 0) ? atomicAdd(&bcnt[tid], v) : 0;
    __syncthreads();

    for (int i = tid; i < NBK; i += SC_THREADS) h[i] = 0;
    __syncthreads();

    for (int i = tid; i < n; i += SC_THREADS) {
        const int s = ei[e0 + i];
        const int t = ei[N_EDGES + e0 + i];
        const int bk = s >> 8;
        const int c = atomicAdd(&h[bk], 1);
        stage[lofs[bk] + c] = (unsigned int)t | ((unsigned int)(s & 255) << 17);
    }
    __syncthreads();

    for (int bk = wid; bk < NBK; bk += SC_THREADS / 64) {
        const int cnt = h[bk];
        const int lo = lofs[bk];
        unsigned int* dst = bbuf + (size_t)bk * BCAP + gbase[bk];
        for (int i = lane; i < cnt; i += 64) dst[i] = stage[lo + i];
    }
}

// ---------------- Fused CSR build: deg + off + sorted_t (1 block/bucket) ----
__global__ __launch_bounds__(256) void csr_build(const int* __restrict__ bcnt,
                                                 const unsigned int* __restrict__ bbuf,
                                                 int* __restrict__ deg,
                                                 int* __restrict__ off,
                                                 int* __restrict__ sorted_t) {
    __shared__ int h[256];
    __shared__ int lofs[256];
    __shared__ int wsum[4];
    __shared__ int sBase;

    const int tid = threadIdx.x;
    const int lane = tid & 63;
    const int wid = tid >> 6;
    const int bk = blockIdx.x;
    const int n = bcnt[bk];

    int pre = 0;
    for (int i = tid; i < bk; i += 256) pre += bcnt[i];
    #pragma unroll
    for (int d = 1; d < 64; d <<= 1) pre += __shfl_xor(pre, d);
    if (lane == 0) wsum[wid] = pre;
    h[tid] = 0;
    __syncthreads();
    if (tid == 0) sBase = wsum[0] + wsum[1] + wsum[2] + wsum[3];
    __syncthreads();

    const unsigned int* p = bbuf + (size_t)bk * BCAP;
    for (int i = tid; i < n; i += 256)
        atomicAdd(&h[p[i] >> 17], 1);
    __syncthreads();

    const int v = h[tid];
    int inc = v;
    #pragma unroll
    for (int d = 1; d < 64; d <<= 1) {
        int u = __shfl_up(inc, d);
        if (lane >= d) inc += u;
    }
    if (lane == 63) wsum[wid] = inc;
    __syncthreads();
    int woff = 0;
    for (int w = 0; w < wid; ++w) woff += wsum[w];
    const int exc = woff + inc - v;
    lofs[tid] = exc;
    const int node = bk * 256 + tid;
    if (node < N_NODES) { deg[node] = v; off[node] = sBase + exc; }
    __syncthreads();

    h[tid] = 0;
    __syncthreads();
    int* dstbase = sorted_t + sBase;
    for (int i = tid; i < n; i += 256) {
        const unsigned int e = p[i];
        const int s8 = e >> 17;
        const int c = atomicAdd(&h[s8], 1);
        dstbase[lofs[s8] + c] = (int)(e & 0x1FFFFu);
    }
}

// ---------------- Fused per-node attention ----------------
// One wave per node; 16 edges per step (4 per eg slot, 4 gathers in flight).
// lane = eg*16 + q16. Logits in log2 domain (exp2f). DPP quad-reduce for dots.
__global__ __launch_bounds__(256) void node_pass(const unsigned short* __restrict__ qkv,
                                                 const int* __restrict__ off,
                                                 const int* __restrict__ deg,
                                                 const int* __restrict__ sorted_t,
                                                 float* __restrict__ out) {
    const int node = blockIdx.x * 4 + (threadIdx.x >> 6);
    const int lane = threadIdx.x & 63;
    if (node >= N_NODES) return;
    const int eg = lane >> 4;
    const int q16 = lane & 15;

    const int o = off[node];
    const int d = deg[node];

    // q (log2-domain, bf16): lane's 4 dims = 2 pairs
    const uint2 qu = *(const uint2*)(qkv + (size_t)node * 192 + q16 * 4);
    const float qx = bf_lo(qu.x), qy = bf_hi(qu.x);
    const float qz = bf_lo(qu.y), qw = bf_hi(qu.y);

    const float NEG_INF = -__builtin_inff();
    float m = NEG_INF;
    float l = 0.f;
    float4 acc = make_float4(0.f, 0.f, 0.f, 0.f);

    for (int base = 0; base < d; base += 64) {
        const int nb = min(64, d - base);
        int tb = (base + lane < d) ? sorted_t[o + base + lane] : 0;
        for (int j16 = 0; j16 < nb; j16 += 16) {
            const int i0 = j16 + eg;
            const int t0 = __shfl(tb, i0);
            const int t1 = __shfl(tb, i0 + 4);
            const int t2 = __shfl(tb, i0 + 8);
            const int t3 = __shfl(tb, i0 + 12);
            const uint4 A0 = *(const uint4*)(qkv + (size_t)t0 * 192 + 64 + q16 * 8);
            const uint4 A1 = *(const uint4*)(qkv + (size_t)t1 * 192 + 64 + q16 * 8);
            const uint4 A2 = *(const uint4*)(qkv + (size_t)t2 * 192 + 64 + q16 * 8);
            const uint4 A3 = *(const uint4*)(qkv + (size_t)t3 * 192 + 64 + q16 * 8);
            float p0 = qx * bf_lo(A0.x) + qy * bf_hi(A0.x) + qz * bf_lo(A0.y) + qw * bf_hi(A0.y);
            float p1 = qx * bf_lo(A1.x) + qy * bf_hi(A1.x) + qz * bf_lo(A1.y) + qw * bf_hi(A1.y);
            float p2 = qx * bf_lo(A2.x) + qy * bf_hi(A2.x) + qz * bf_lo(A2.y) + qw * bf_hi(A2.y);
            float p3 = qx * bf_lo(A3.x) + qy * bf_hi(A3.x) + qz * bf_lo(A3.y) + qw * bf_hi(A3.y);
            p0 = qsum4(p0); p1 = qsum4(p1); p2 = qsum4(p2); p3 = qsum4(p3);
            p0 = (i0      < nb) ? p0 : NEG_INF;
            p1 = (i0 + 4  < nb) ? p1 : NEG_INF;
            p2 = (i0 + 8  < nb) ? p2 : NEG_INF;
            p3 = (i0 + 12 < nb) ? p3 : NEG_INF;
            float pm = fmaxf(fmaxf(p0, p1), fmaxf(p2, p3));
            pm = fmaxf(pm, __shfl_xor(pm, 16));
            pm = fmaxf(pm, __shfl_xor(pm, 32));   // per-head max over the 16 edges
            if (__any(pm > m)) {
                const float nm = fmaxf(m, pm);
                const float sc = exp2f(m - nm);
                l *= sc;
                acc.x *= sc; acc.y *= sc; acc.z *= sc; acc.w *= sc;
                m = nm;
            }
            const float e0 = exp2f(p0 - m);       // 0 for masked slots
            const float e1 = exp2f(p1 - m);
            const float e2 = exp2f(p2 - m);
            const float e3 = exp2f(p3 - m);
            l += (e0 + e1) + (e2 + e3);
            acc.x = fmaf(e0, bf_lo(A0.z), fmaf(e1, bf_lo(A1.z),
                    fmaf(e2, bf_lo(A2.z), fmaf(e3, bf_lo(A3.z), acc.x))));
            acc.y = fmaf(e0, bf_hi(A0.z), fmaf(e1, bf_hi(A1.z),
                    fmaf(e2, bf_hi(A2.z), fmaf(e3, bf_hi(A3.z), acc.y))));
            acc.z = fmaf(e0, bf_lo(A0.w), fmaf(e1, bf_lo(A1.w),
                    fmaf(e2, bf_lo(A2.w), fmaf(e3, bf_lo(A3.w), acc.z))));
            acc.w = fmaf(e0, bf_hi(A0.w), fmaf(e1, bf_hi(A1.w),
                    fmaf(e2, bf_hi(A2.w), fmaf(e3, bf_hi(A3.w), acc.w))));
        }
    }
    l += __shfl_xor(l, 16);  l += __shfl_xor(l, 32);
    acc.x += __shfl_xor(acc.x, 16);  acc.x += __shfl_xor(acc.x, 32);
    acc.y += __shfl_xor(acc.y, 16);  acc.y += __shfl_xor(acc.y, 32);
    acc.z += __shfl_xor(acc.z, 16);  acc.z += __shfl_xor(acc.z, 32);
    acc.w += __shfl_xor(acc.w, 16);  acc.w += __shfl_xor(acc.w, 32);

    if (eg == 0) {
        const float inv = 1.f / (l + EPS);
        float4 r = make_float4(acc.x * inv, acc.y * inv, acc.z * inv, acc.w * inv);
        *(float4*)(out + (size_t)node * DIM + q16 * 4) = r;
    }
}

extern "C" void kernel_launch(void* const* d_in, const int* in_sizes, int n_in,
                              void* d_out, int out_size, void* d_ws, size_t ws_size,
                              hipStream_t stream) {
    const float* x = (const float*)d_in[0];
    const float* W = (const float*)d_in[1];
    const float* b = (const float*)d_in[2];
    const int*   ei = (const int*)d_in[3];   // (2, E): [0:E]=src, [E:2E]=tgt
    float* out = (float*)d_out;

    // workspace: qkv_t 38.4MB | bbuf 12.8MB | sorted_t 6.4MB | deg | off | bcnt | Wbt | bb
    unsigned short* qkv_t = (unsigned short*)d_ws;
    unsigned int* bbuf = (unsigned int*)(qkv_t + (size_t)N_NODES * 192);
    int* sorted_t = (int*)(bbuf + (size_t)NBK * BCAP);
    int* deg      = sorted_t + N_EDGES;
    int* off      = deg + N_NODES;
    int* bcnt     = off + N_NODES;
    unsigned short* Wbt = (unsigned short*)(bcnt + NBK);   // 192*64 bf16
    float* bb     = (float*)(Wbt + 192 * DIM);             // 192 f32

    prep_w<<<64, 192, 0, stream>>>(W, b, Wbt, bb, bcnt);
    qkv_mfma<<<(N_NODES + 63) / 64, 256, 0, stream>>>(x, Wbt, bb, qkv_t);
    bucket_scatter<<<SC_BLOCKS, SC_THREADS, 0, stream>>>(ei, bcnt, bbuf);
    csr_build<<<NBK, 256, 0, stream>>>(bcnt, bbuf, deg, off, sorted_t);
    node_pass<<<(N_NODES + 3) / 4, 256, 0, stream>>>(qkv_t, off, deg, sorted_t, out);
}

// Round 11
// 128.654 us; speedup vs baseline: 47.7887x; 1.0504x over previous
//
#include <hip/hip_runtime.h>

// SelfAttentionBlock: graph transformer attention
// N=100000 nodes, E=1600000 edges, DIM=64, H=4 heads, d=16
constexpr int N_NODES = 100000;
constexpr int N_EDGES = 1600000;
constexpr int DIM = 64;
constexpr float QK_SCALE = 0.25f;   // 16^-0.5
constexpr float LOG2E = 1.4426950408889634f;
constexpr float EPS = 1e-16f;

// bucket sort: bucket = s>>8 (256 nodes each)
constexpr int NBK = (N_NODES + 255) / 256;    // 391
constexpr int BCAP = 8192;                    // u32/bucket
constexpr int SC_CHUNK = 8192;                // edges per scatter block
constexpr int SC_BLOCKS = (N_EDGES + SC_CHUNK - 1) / SC_CHUNK;  // 196
constexpr int QK_BLOCKS = (N_NODES + 127) / 128;                // 782 (128 nodes/block)

typedef __attribute__((ext_vector_type(8))) short short8;   // 8 bf16 (4 VGPR)
typedef __attribute__((ext_vector_type(4))) float f32x4;

__device__ __forceinline__ unsigned short f32_to_bf16_rne(float f) {
    unsigned int u = __float_as_uint(f);
    u += 0x7fffu + ((u >> 16) & 1u);          // round-to-nearest-even
    return (unsigned short)(u >> 16);
}
__device__ __forceinline__ float bf_lo(unsigned int u) { return __uint_as_float(u << 16); }
__device__ __forceinline__ float bf_hi(unsigned int u) { return __uint_as_float(u & 0xffff0000u); }

// sum over 4-lane quad via DPP (quad_perm xor1 = 0xB1, xor2 = 0x4E) - pure VALU
__device__ __forceinline__ float qsum4(float p) {
    int a = __builtin_amdgcn_update_dpp(0, __float_as_int(p), 0xB1, 0xF, 0xF, true);
    p += __int_as_float(a);
    int c = __builtin_amdgcn_update_dpp(0, __float_as_int(p), 0x4E, 0xF, 0xF, true);
    p += __int_as_float(c);
    return p;
}

// permuted output column jp -> original W column.
// jp 0..63: q cols. jp 64..191: interleaved kv layout [k0..3 v0..3 k4..7 ...]
__device__ __forceinline__ int orig_col(int jp) {
    if (jp < 64) return jp;
    const int p = jp - 64;
    const int chunk = p >> 3, w = p & 7;
    return (w < 4) ? (64 + chunk * 4 + w) : (128 + chunk * 4 + (w - 4));
}

// ---------------- prep: Wbt[jp][k] bf16 (permuted cols; q cols scaled by
// QK_SCALE*log2e for exp2-domain softmax), bias bb[jp] f32, bcnt zeroing.
__global__ __launch_bounds__(192) void prep_w(const float* __restrict__ W,
                                              const float* __restrict__ b,
                                              unsigned short* __restrict__ Wbt,
                                              float* __restrict__ bb,
                                              int* __restrict__ bcnt) {
    const int jp = threadIdx.x;
    const int k = blockIdx.x;
    const int oc = orig_col(jp);
    const float sc = (jp < 64) ? QK_SCALE * LOG2E : 1.f;
    Wbt[jp * DIM + k] = f32_to_bf16_rne(W[k * 192 + oc] * sc);
    if (k == 0) {
        bb[jp] = b[oc] * sc;
        for (int i = jp; i < NBK; i += 192) bcnt[i] = 0;
    }
}

// ---------------- Packed kernel: bucket_scatter (blocks 0..SC_BLOCKS-1)
//                  + qkv projection via MFMA (remaining blocks) -------------
// Independent work items run concurrently in one dispatch (one stream, no
// cross-stream capture). Scatter blocks first so they start immediately.
__global__ __launch_bounds__(512) void proj_scatter(const float* __restrict__ x,
                                                    const unsigned short* __restrict__ Wbt,
                                                    const float* __restrict__ bb,
                                                    unsigned short* __restrict__ qkv_t,
                                                    const int* __restrict__ ei,
                                                    int* __restrict__ bcnt,
                                                    unsigned int* __restrict__ bbuf) {
    __shared__ int h[NBK];          // hist -> cursors
    __shared__ int lofs[NBK];       // local exclusive offsets
    __shared__ int gbase[NBK];      // global base per bucket
    __shared__ int wsum[8];
    __shared__ unsigned int stage[SC_CHUNK];

    if (blockIdx.x < SC_BLOCKS) {
        // ---------- bucket scatter with LDS dense staging ----------
        // Payload packed: bits 0..16 = t, bits 17..24 = s&255.
        const int tid = threadIdx.x;
        const int lane = tid & 63;
        const int wid = tid >> 6;
        const int e0 = blockIdx.x * SC_CHUNK;
        const int n = min(SC_CHUNK, N_EDGES - e0);

        for (int i = tid; i < NBK; i += 512) h[i] = 0;
        __syncthreads();

        for (int i = tid; i < n; i += 512)
            atomicAdd(&h[ei[e0 + i] >> 8], 1);
        __syncthreads();

        const int v = (tid < NBK) ? h[tid] : 0;
        int inc = v;
        #pragma unroll
        for (int d = 1; d < 64; d <<= 1) {
            int u = __shfl_up(inc, d);
            if (lane >= d) inc += u;
        }
        if (lane == 63) wsum[wid] = inc;
        __syncthreads();
        int woff = 0;
        for (int w = 0; w < wid; ++w) woff += wsum[w];
        if (tid < NBK) lofs[tid] = woff + inc - v;
        if (tid < NBK) gbase[tid] = (v > 0) ? atomicAdd(&bcnt[tid], v) : 0;
        __syncthreads();

        for (int i = tid; i < NBK; i += 512) h[i] = 0;
        __syncthreads();

        for (int i = tid; i < n; i += 512) {
            const int s = ei[e0 + i];
            const int t = ei[N_EDGES + e0 + i];
            const int bk = s >> 8;
            const int c = atomicAdd(&h[bk], 1);
            stage[lofs[bk] + c] = (unsigned int)t | ((unsigned int)(s & 255) << 17);
        }
        __syncthreads();

        for (int bk = wid; bk < NBK; bk += 8) {
            const int cnt = h[bk];
            const int lo = lofs[bk];
            unsigned int* dst = bbuf + (size_t)bk * BCAP + gbase[bk];
            for (int i = lane; i < cnt; i += 64) dst[i] = stage[lo + i];
        }
    } else {
        // ---------- qkv projection via MFMA (wave = 16 nodes x 192 cols) ----
        // A frag: lane holds x[row=l&15][k=(l>>4)*8+i]; B frag: Wbt[col][k].
        // D: col = l&15, row = (l>>4)*4 + reg  (m89-verified).
        const int lane = threadIdx.x & 63;
        const int wid = threadIdx.x >> 6;
        const int n0 = (blockIdx.x - SC_BLOCKS) * 128 + wid * 16;
        if (n0 >= N_NODES) return;                 // wave-uniform
        const int row = lane & 15;
        const int kg = lane >> 4;

        const int nidx = min(n0 + row, N_NODES - 1);
        const float* xr = x + (size_t)nidx * DIM + kg * 8;
        short8 a0, a1;
        {
            const float4 u0 = *(const float4*)(xr);
            const float4 u1 = *(const float4*)(xr + 4);
            const float4 u2 = *(const float4*)(xr + 32);
            const float4 u3 = *(const float4*)(xr + 36);
            a0[0] = (short)f32_to_bf16_rne(u0.x); a0[1] = (short)f32_to_bf16_rne(u0.y);
            a0[2] = (short)f32_to_bf16_rne(u0.z); a0[3] = (short)f32_to_bf16_rne(u0.w);
            a0[4] = (short)f32_to_bf16_rne(u1.x); a0[5] = (short)f32_to_bf16_rne(u1.y);
            a0[6] = (short)f32_to_bf16_rne(u1.z); a0[7] = (short)f32_to_bf16_rne(u1.w);
            a1[0] = (short)f32_to_bf16_rne(u2.x); a1[1] = (short)f32_to_bf16_rne(u2.y);
            a1[2] = (short)f32_to_bf16_rne(u2.z); a1[3] = (short)f32_to_bf16_rne(u2.w);
            a1[4] = (short)f32_to_bf16_rne(u3.x); a1[5] = (short)f32_to_bf16_rne(u3.y);
            a1[6] = (short)f32_to_bf16_rne(u3.z); a1[7] = (short)f32_to_bf16_rne(u3.w);
        }

        #pragma unroll
        for (int ct = 0; ct < 12; ++ct) {
            const int c0 = ct * 16;
            const float bias = bb[c0 + row];
            f32x4 acc = {bias, bias, bias, bias};
            const short8 b0 = *(const short8*)(Wbt + (c0 + row) * DIM + kg * 8);
            const short8 b1 = *(const short8*)(Wbt + (c0 + row) * DIM + kg * 8 + 32);
            acc = __builtin_amdgcn_mfma_f32_16x16x32_bf16(a0, b0, acc, 0, 0, 0);
            acc = __builtin_amdgcn_mfma_f32_16x16x32_bf16(a1, b1, acc, 0, 0, 0);

            const int colg = c0 + row;
            #pragma unroll
            for (int r = 0; r < 4; ++r) {
                const int node = n0 + kg * 4 + r;
                if (node < N_NODES)
                    qkv_t[(size_t)node * 192 + colg] = f32_to_bf16_rne(acc[r]);
            }
        }
    }
}

// ---------------- Fused CSR build: deg + off + sorted_t (1 block/bucket) ----
__global__ __launch_bounds__(256) void csr_build(const int* __restrict__ bcnt,
                                                 const unsigned int* __restrict__ bbuf,
                                                 int* __restrict__ deg,
                                                 int* __restrict__ off,
                                                 int* __restrict__ sorted_t) {
    __shared__ int h[256];
    __shared__ int lofs[256];
    __shared__ int wsum[4];
    __shared__ int sBase;

    const int tid = threadIdx.x;
    const int lane = tid & 63;
    const int wid = tid >> 6;
    const int bk = blockIdx.x;
    const int n = bcnt[bk];

    int pre = 0;
    for (int i = tid; i < bk; i += 256) pre += bcnt[i];
    #pragma unroll
    for (int d = 1; d < 64; d <<= 1) pre += __shfl_xor(pre, d);
    if (lane == 0) wsum[wid] = pre;
    h[tid] = 0;
    __syncthreads();
    if (tid == 0) sBase = wsum[0] + wsum[1] + wsum[2] + wsum[3];
    __syncthreads();

    const unsigned int* p = bbuf + (size_t)bk * BCAP;
    for (int i = tid; i < n; i += 256)
        atomicAdd(&h[p[i] >> 17], 1);
    __syncthreads();

    const int v = h[tid];
    int inc = v;
    #pragma unroll
    for (int d = 1; d < 64; d <<= 1) {
        int u = __shfl_up(inc, d);
        if (lane >= d) inc += u;
    }
    if (lane == 63) wsum[wid] = inc;
    __syncthreads();
    int woff = 0;
    for (int w = 0; w < wid; ++w) woff += wsum[w];
    const int exc = woff + inc - v;
    lofs[tid] = exc;
    const int node = bk * 256 + tid;
    if (node < N_NODES) { deg[node] = v; off[node] = sBase + exc; }
    __syncthreads();

    h[tid] = 0;
    __syncthreads();
    int* dstbase = sorted_t + sBase;
    for (int i = tid; i < n; i += 256) {
        const unsigned int e = p[i];
        const int s8 = e >> 17;
        const int c = atomicAdd(&h[s8], 1);
        dstbase[lofs[s8] + c] = (int)(e & 0x1FFFFu);
    }
}

// ---------------- Fused per-node attention ----------------
// One wave per node; 16 edges per step. Group eg owns CONSECUTIVE edges
// j+4eg..j+4eg+3 -> its 4 targets load directly from sorted_t (same addr
// across the 16-lane group, HW-merged) — no ds_bpermute anywhere in the loop.
// Per-group online max with exact end-merge (split softmax). Finite
// sentinels (no NaN paths): init m=-1e30, masked logit=-2e30.
__global__ __launch_bounds__(256) void node_pass(const unsigned short* __restrict__ qkv,
                                                 const int* __restrict__ off,
                                                 const int* __restrict__ deg,
                                                 const int* __restrict__ sorted_t,
                                                 float* __restrict__ out) {
    const int node = blockIdx.x * 4 + (threadIdx.x >> 6);
    const int lane = threadIdx.x & 63;
    if (node >= N_NODES) return;
    const int eg = lane >> 4;
    const int q16 = lane & 15;

    const int o = off[node];
    const int d = deg[node];

    // q (log2-domain, bf16): lane's 4 dims = 2 pairs
    const uint2 qu = *(const uint2*)(qkv + (size_t)node * 192 + q16 * 4);
    const float qx = bf_lo(qu.x), qy = bf_hi(qu.x);
    const float qz = bf_lo(qu.y), qw = bf_hi(qu.y);

    const float M0 = -1e30f, MASKV = -2e30f;
    float m = M0;
    float l = 0.f;
    float4 acc = make_float4(0.f, 0.f, 0.f, 0.f);

    for (int j = 0; j < d; j += 16) {
        const int b0 = j + eg * 4;
        const int dm = d - 1;
        const int t0 = sorted_t[o + min(b0,     dm)];
        const int t1 = sorted_t[o + min(b0 + 1, dm)];
        const int t2 = sorted_t[o + min(b0 + 2, dm)];
        const int t3 = sorted_t[o + min(b0 + 3, dm)];
        const uint4 A0 = *(const uint4*)(qkv + (size_t)t0 * 192 + 64 + q16 * 8);
        const uint4 A1 = *(const uint4*)(qkv + (size_t)t1 * 192 + 64 + q16 * 8);
        const uint4 A2 = *(const uint4*)(qkv + (size_t)t2 * 192 + 64 + q16 * 8);
        const uint4 A3 = *(const uint4*)(qkv + (size_t)t3 * 192 + 64 + q16 * 8);
        float p0 = qx * bf_lo(A0.x) + qy * bf_hi(A0.x) + qz * bf_lo(A0.y) + qw * bf_hi(A0.y);
        float p1 = qx * bf_lo(A1.x) + qy * bf_hi(A1.x) + qz * bf_lo(A1.y) + qw * bf_hi(A1.y);
        float p2 = qx * bf_lo(A2.x) + qy * bf_hi(A2.x) + qz * bf_lo(A2.y) + qw * bf_hi(A2.y);
        float p3 = qx * bf_lo(A3.x) + qy * bf_hi(A3.x) + qz * bf_lo(A3.y) + qw * bf_hi(A3.y);
        p0 = qsum4(p0); p1 = qsum4(p1); p2 = qsum4(p2); p3 = qsum4(p3);
        p0 = (b0     < d) ? p0 : MASKV;
        p1 = (b0 + 1 < d) ? p1 : MASKV;
        p2 = (b0 + 2 < d) ? p2 : MASKV;
        p3 = (b0 + 3 < d) ? p3 : MASKV;
        const float pm = fmaxf(fmaxf(p0, p1), fmaxf(p2, p3));   // this group's max
        if (__any(pm > m)) {
            const float nm = fmaxf(m, pm);
            const float sc = exp2f(m - nm);    // finite-finite: no NaN
            l *= sc;
            acc.x *= sc; acc.y *= sc; acc.z *= sc; acc.w *= sc;
            m = nm;
        }
        const float e0 = exp2f(p0 - m);        // masked: exp2(~-1e30) = 0
        const float e1 = exp2f(p1 - m);
        const float e2 = exp2f(p2 - m);
        const float e3 = exp2f(p3 - m);
        l += (e0 + e1) + (e2 + e3);
        acc.x = fmaf(e0, bf_lo(A0.z), fmaf(e1, bf_lo(A1.z),
                fmaf(e2, bf_lo(A2.z), fmaf(e3, bf_lo(A3.z), acc.x))));
        acc.y = fmaf(e0, bf_hi(A0.z), fmaf(e1, bf_hi(A1.z),
                fmaf(e2, bf_hi(A2.z), fmaf(e3, bf_hi(A3.z), acc.y))));
        acc.z = fmaf(e0, bf_lo(A0.w), fmaf(e1, bf_lo(A1.w),
                fmaf(e2, bf_lo(A2.w), fmaf(e3, bf_lo(A3.w), acc.z))));
        acc.w = fmaf(e0, bf_hi(A0.w), fmaf(e1, bf_hi(A1.w),
                fmaf(e2, bf_hi(A2.w), fmaf(e3, bf_hi(A3.w), acc.w))));
    }

    // exact split-softmax merge across the 4 edge-groups
    float M = fmaxf(m, __shfl_xor(m, 16));
    M = fmaxf(M, __shfl_xor(M, 32));
    const float s = exp2f(m - M);              // empty group: exp2(-1e30)=0; d==0: exp2(0)=1, l=0
    l *= s;
    acc.x *= s; acc.y *= s; acc.z *= s; acc.w *= s;

    l += __shfl_xor(l, 16);  l += __shfl_xor(l, 32);
    acc.x += __shfl_xor(acc.x, 16);  acc.x += __shfl_xor(acc.x, 32);
    acc.y += __shfl_xor(acc.y, 16);  acc.y += __shfl_xor(acc.y, 32);
    acc.z += __shfl_xor(acc.z, 16);  acc.z += __shfl_xor(acc.z, 32);
    acc.w += __shfl_xor(acc.w, 16);  acc.w += __shfl_xor(acc.w, 32);

    if (eg == 0) {
        const float inv = 1.f / (l + EPS);
        float4 r = make_float4(acc.x * inv, acc.y * inv, acc.z * inv, acc.w * inv);
        *(float4*)(out + (size_t)node * DIM + q16 * 4) = r;
    }
}

extern "C" void kernel_launch(void* const* d_in, const int* in_sizes, int n_in,
                              void* d_out, int out_size, void* d_ws, size_t ws_size,
                              hipStream_t stream) {
    const float* x = (const float*)d_in[0];
    const float* W = (const float*)d_in[1];
    const float* b = (const float*)d_in[2];
    const int*   ei = (const int*)d_in[3];   // (2, E): [0:E]=src, [E:2E]=tgt
    float* out = (float*)d_out;

    // workspace: qkv_t 38.4MB | bbuf 12.8MB | sorted_t 6.4MB | deg | off | bcnt | Wbt | bb
    unsigned short* qkv_t = (unsigned short*)d_ws;
    unsigned int* bbuf = (unsigned int*)(qkv_t + (size_t)N_NODES * 192);
    int* sorted_t = (int*)(bbuf + (size_t)NBK * BCAP);
    int* deg      = sorted_t + N_EDGES;
    int* off      = deg + N_NODES;
    int* bcnt     = off + N_NODES;
    unsigned short* Wbt = (unsigned short*)(bcnt + NBK);   // 192*64 bf16
    float* bb     = (float*)(Wbt + 192 * DIM);             // 192 f32

    prep_w<<<64, 192, 0, stream>>>(W, b, Wbt, bb, bcnt);
    proj_scatter<<<SC_BLOCKS + QK_BLOCKS, 512, 0, stream>>>(x, Wbt, bb, qkv_t, ei, bcnt, bbuf);
    csr_build<<<NBK, 256, 0, stream>>>(bcnt, bbuf, deg, off, sorted_t);
    node_pass<<<(N_NODES + 3) / 4, 256, 0, stream>>>(qkv_t, off, deg, sorted_t, out);
}